// Round 3
// baseline (456.919 us; speedup 1.0000x reference)
//
#include <hip/hip_runtime.h>
#include <cstdint>
#include <cstddef>

// ---------- types ----------
typedef __attribute__((ext_vector_type(8))) short short8;   // 8 bf16 (4 VGPRs)
typedef __attribute__((ext_vector_type(4))) short short4v;  // 4 bf16
typedef __attribute__((ext_vector_type(4))) float f32x4;    // MFMA accum

__device__ __forceinline__ short f2bf(float f) {
    union { float f; unsigned u; } c; c.f = f;
    unsigned r = c.u + 0x7fffu + ((c.u >> 16) & 1u);   // RNE
    return (short)(r >> 16);
}

// async global->LDS, 16B per lane; LDS dest must be wave-uniform base + lane*16
__device__ __forceinline__ void gl2lds16(const void* g, void* l) {
    __builtin_amdgcn_global_load_lds(
        (const __attribute__((address_space(1))) void*)g,
        (__attribute__((address_space(3))) void*)l, 16, 0, 0);
}

// ---------- 1. weight convert/transpose (bf16) via LDS tile (coalesced) ----------
__global__ __launch_bounds__(256) void wconv(
    const float* __restrict__ S, short* __restrict__ D, int K, int N, float scale)
{
    __shared__ float t[32][33];
    const int kt = blockIdx.x * 32, nt = blockIdx.y * 32;
    const int x = threadIdx.x & 31, y4 = (threadIdx.x >> 5) * 4;
    for (int i = 0; i < 4; i++)
        t[y4 + i][x] = S[(size_t)(kt + y4 + i) * N + nt + x];
    __syncthreads();
    for (int i = 0; i < 4; i++)
        D[(size_t)(nt + y4 + i) * K + kt + x] = f2bf(t[x][y4 + i] * scale);
}

// ---------- 2. LayerNorm -> bf16, one WAVE per row (no barriers, no LDS) ----------
__global__ __launch_bounds__(256) void ln_kernel(
    const float* __restrict__ x, const float* __restrict__ lat,
    const float* __restrict__ gx, const float* __restrict__ bx,
    const float* __restrict__ gl, const float* __restrict__ bl,
    short* __restrict__ Aout, short* __restrict__ Lq)
{
    const int wave = threadIdx.x >> 6, lane = threadIdx.x & 63;
    const int r = blockIdx.x * 4 + wave;   // 0..33791
    const float *src, *g, *b; size_t drow; short* dst2 = nullptr;
    if (r < 32768) {
        int bt = r >> 11, i = r & 2047;
        src = x + (size_t)r * 1024; g = gx; b = bx;
        drow = (size_t)bt * 2112 + i;
    } else {
        int idx = r - 32768;
        int bt = idx >> 6, i = idx & 63;
        src = lat + (size_t)idx * 1024; g = gl; b = bl;
        drow = (size_t)bt * 2112 + 2048 + i;
        dst2 = Lq + (size_t)idx * 1024;
    }
    float4 v[4];
    for (int j = 0; j < 4; j++) v[j] = ((const float4*)src)[lane + 64 * j];
    float s = 0.f, s2 = 0.f;
    for (int j = 0; j < 4; j++) {
        s  += v[j].x + v[j].y + v[j].z + v[j].w;
        s2 += v[j].x * v[j].x + v[j].y * v[j].y + v[j].z * v[j].z + v[j].w * v[j].w;
    }
    for (int off = 32; off >= 1; off >>= 1) { s += __shfl_xor(s, off); s2 += __shfl_xor(s2, off); }
    const float mu   = s * (1.f / 1024.f);
    const float rstd = rsqrtf(s2 * (1.f / 1024.f) - mu * mu + 1e-5f);
    for (int j = 0; j < 4; j++) {
        float4 gv = ((const float4*)g)[lane + 64 * j];
        float4 bv = ((const float4*)b)[lane + 64 * j];
        short4v o;
        o[0] = f2bf((v[j].x - mu) * rstd * gv.x + bv.x);
        o[1] = f2bf((v[j].y - mu) * rstd * gv.y + bv.y);
        o[2] = f2bf((v[j].z - mu) * rstd * gv.z + bv.z);
        o[3] = f2bf((v[j].w - mu) * rstd * gv.w + bv.w);
        *(short4v*)(Aout + drow * 1024 + (size_t)(lane + 64 * j) * 4) = o;
        if (dst2) *(short4v*)(dst2 + (size_t)(lane + 64 * j) * 4) = o;
    }
}

// ---------- 3. bf16 GEMM, C = A(MxK)*Bt(NxK)^T, 128x128 tile; grid (nTiles, mTiles)
// x = n-panel (fastest) so linear%8 = XCD = n-panel -> B-panel L2-resident per XCD
template <typename OutT>
__global__ __launch_bounds__(256) void gemm_bt(
    const short* __restrict__ A, const short* __restrict__ Bt,
    OutT* __restrict__ C, int N, int K)
{
    __shared__ short As[128 * 32];
    __shared__ short Bs[128 * 32];
    const int tid  = threadIdx.x;
    const int wave = tid >> 6, lane = tid & 63;
    const int col  = lane & 15, quad = lane >> 4;
    const int n0 = blockIdx.x * 128, m0 = blockIdx.y * 128;
    const int wm = (wave >> 1) * 64, wn = (wave & 1) * 64;
    const int sr = tid >> 2;           // staging row 0..63
    const int sk = (tid & 3) * 8;      // staging k offset

    f32x4 acc[4][4];
    for (int i = 0; i < 4; i++) for (int j = 0; j < 4; j++) acc[i][j] = f32x4{0.f, 0.f, 0.f, 0.f};

    const short* Ar0 = A  + (size_t)(m0 + sr)      * K + sk;
    const short* Ar1 = A  + (size_t)(m0 + sr + 64) * K + sk;
    const short* Br0 = Bt + (size_t)(n0 + sr)      * K + sk;
    const short* Br1 = Bt + (size_t)(n0 + sr + 64) * K + sk;
    short* lA0 = &As[sr * 32 + sk];
    short* lA1 = &As[(sr + 64) * 32 + sk];
    short* lB0 = &Bs[sr * 32 + sk];
    short* lB1 = &Bs[(sr + 64) * 32 + sk];

    for (int k0 = 0; k0 < K; k0 += 32) {
        __syncthreads();
        gl2lds16(Ar0 + k0, lA0);
        gl2lds16(Ar1 + k0, lA1);
        gl2lds16(Br0 + k0, lB0);
        gl2lds16(Br1 + k0, lB1);
        __syncthreads();
        short8 af[4], bf[4];
        for (int mt = 0; mt < 4; mt++) af[mt] = *(const short8*)&As[(wm + mt * 16 + col) * 32 + quad * 8];
        for (int nt = 0; nt < 4; nt++) bf[nt] = *(const short8*)&Bs[(wn + nt * 16 + col) * 32 + quad * 8];
        for (int mt = 0; mt < 4; mt++)
            for (int nt = 0; nt < 4; nt++)
                acc[mt][nt] = __builtin_amdgcn_mfma_f32_16x16x32_bf16(af[mt], bf[nt], acc[mt][nt], 0, 0, 0);
    }
    for (int mt = 0; mt < 4; mt++)
        for (int nt = 0; nt < 4; nt++)
            for (int r = 0; r < 4; r++) {
                int row = m0 + wm + mt * 16 + quad * 4 + r;
                int cc  = n0 + wn + nt * 16 + col;
                float v = acc[mt][nt][r];
                if constexpr (sizeof(OutT) == 2) C[(size_t)row * N + cc] = (OutT)f2bf(v);
                else                             C[(size_t)row * N + cc] = v;
            }
}

// ---------- 4. transpose V: KV[bt*2112+j][512+h*64+d] -> Vt[(bt*8+h)*64+d][j] ----------
__global__ __launch_bounds__(256) void transpose_v(const short* __restrict__ KV, short* __restrict__ Vt)
{
    __shared__ short tile[64 * 68];
    const int bth = blockIdx.y, bt = bth >> 3, h = bth & 7;
    const int jt = blockIdx.x * 64;
    const int tid = threadIdx.x;
    for (int it = 0; it < 2; ++it) {
        int s = tid + it * 256;
        int j = s >> 3, dv = (s & 7) * 8;
        short8 v = *(const short8*)(KV + (size_t)(bt * 2112 + jt + j) * 1024 + 512 + h * 64 + dv);
        short4v lo = {v[0], v[1], v[2], v[3]}, hi = {v[4], v[5], v[6], v[7]};
        *(short4v*)&tile[j * 68 + dv]     = lo;
        *(short4v*)&tile[j * 68 + dv + 4] = hi;
    }
    __syncthreads();
    for (int it = 0; it < 2; ++it) {
        int s = tid + it * 256;
        int d = s >> 3, jv = (s & 7) * 8;
        short8 o;
        for (int jj = 0; jj < 8; jj++) o[jj] = tile[(jv + jj) * 68 + d];
        *(short8*)(Vt + (size_t)(bth * 64 + d) * 2112 + jt + jv) = o;
    }
}

// ---------- 5. attention: grid (128 wg, 8 chunks); un-normalized partials ----------
__global__ __launch_bounds__(256) void attn_kernel(
    const short* __restrict__ Q,    // (1024, 512)
    const short* __restrict__ KV,   // (33792, 1024) k in cols 0..511
    const short* __restrict__ Vt,   // (128*64, 2112)
    float* __restrict__ Opart,      // (1024, 64, 64)
    float* __restrict__ Mp,         // (1024, 64)
    float* __restrict__ Lp)         // (1024, 64)
{
    __shared__ __align__(16) short p_lds[4][64 * 72];   // 36.9 KB; oacc overlays after loop
    __shared__ float sm[4][64];
    __shared__ float sl[4][64];
    float* oacc = (float*)&p_lds[0][0];                 // 16 KB, dead/alive disjoint

    const int wg = blockIdx.x;            // 0..127 = bt*8 + h
    const int ck = blockIdx.y;            // chunk 0..7
    const int wgc = wg * 8 + ck;
    const int bt = wg >> 3, h = wg & 7;
    const int tid = threadIdx.x;
    const int wave = tid >> 6, lane = tid & 63;
    const int col = lane & 15, quad = lane >> 4;

    short8 qf[4][2];
    for (int mt = 0; mt < 4; mt++)
        for (int ks = 0; ks < 2; ks++)
            qf[mt][ks] = *(const short8*)(Q + (size_t)(bt * 64 + mt * 16 + col) * 512
                                            + h * 64 + ks * 32 + quad * 8);

    float m_run[4][4], l_run[4][4];
    f32x4 o_acc[4][4];
    for (int mt = 0; mt < 4; mt++)
        for (int r = 0; r < 4; r++) { m_run[mt][r] = -__builtin_inff(); l_run[mt][r] = 0.f; }
    for (int mt = 0; mt < 4; mt++)
        for (int dt = 0; dt < 4; dt++) o_acc[mt][dt] = f32x4{0.f, 0.f, 0.f, 0.f};

    short* pl = p_lds[wave];

    // 33 key-blocks over 32 (chunk,wave) pairs: pair p handles jb=p (+ jb=32 for p=0)
    for (int jb = ck * 4 + wave; jb < 33; jb += 32) {
        f32x4 s[4][4];
        for (int mt = 0; mt < 4; mt++) for (int nt = 0; nt < 4; nt++) s[mt][nt] = f32x4{0.f, 0.f, 0.f, 0.f};
        for (int nt = 0; nt < 4; nt++) {
            const int j = jb * 64 + nt * 16 + col;
            const short* kp = KV + (size_t)(bt * 2112 + j) * 1024 + h * 64 + quad * 8;
            short8 k0 = *(const short8*)kp;
            short8 k1 = *(const short8*)(kp + 32);
            for (int mt = 0; mt < 4; mt++) {
                s[mt][nt] = __builtin_amdgcn_mfma_f32_16x16x32_bf16(qf[mt][0], k0, s[mt][nt], 0, 0, 0);
                s[mt][nt] = __builtin_amdgcn_mfma_f32_16x16x32_bf16(qf[mt][1], k1, s[mt][nt], 0, 0, 0);
            }
        }
        for (int mt = 0; mt < 4; mt++)
            for (int r = 0; r < 4; r++) {
                float mx = fmaxf(fmaxf(s[mt][0][r], s[mt][1][r]), fmaxf(s[mt][2][r], s[mt][3][r]));
                for (int off = 8; off >= 1; off >>= 1) mx = fmaxf(mx, __shfl_xor(mx, off));
                float mnew = fmaxf(m_run[mt][r], mx);
                float alpha = __expf(m_run[mt][r] - mnew);
                float rs = 0.f;
                for (int nt = 0; nt < 4; nt++) {
                    float p = __expf(s[mt][nt][r] - mnew);
                    s[mt][nt][r] = p;
                    rs += p;
                }
                for (int off = 8; off >= 1; off >>= 1) rs += __shfl_xor(rs, off);
                m_run[mt][r] = mnew;
                l_run[mt][r] = l_run[mt][r] * alpha + rs;
                for (int dt = 0; dt < 4; dt++) o_acc[mt][dt][r] *= alpha;
            }
        for (int mt = 0; mt < 4; mt++)
            for (int nt = 0; nt < 4; nt++)
                for (int r = 0; r < 4; r++)
                    pl[(mt * 16 + quad * 4 + r) * 72 + nt * 16 + col] = f2bf(s[mt][nt][r]);
        for (int ks = 0; ks < 2; ks++) {
            short8 vf[4];
            for (int dt = 0; dt < 4; dt++)
                vf[dt] = *(const short8*)(Vt + (size_t)(wg * 64 + dt * 16 + col) * 2112
                                             + jb * 64 + ks * 32 + quad * 8);
            for (int mt = 0; mt < 4; mt++) {
                short8 pf = *(const short8*)(pl + (mt * 16 + col) * 72 + ks * 32 + quad * 8);
                for (int dt = 0; dt < 4; dt++)
                    o_acc[mt][dt] = __builtin_amdgcn_mfma_f32_16x16x32_bf16(pf, vf[dt], o_acc[mt][dt], 0, 0, 0);
            }
        }
    }

    // ---- merge 4 waves; emit UN-normalized partial (O~, M, L) for this chunk ----
    if (col == 0)
        for (int mt = 0; mt < 4; mt++)
            for (int r = 0; r < 4; r++) {
                int row = mt * 16 + quad * 4 + r;
                sm[wave][row] = m_run[mt][r];
                sl[wave][row] = l_run[mt][r];
            }
    __syncthreads();     // after this, p_lds is dead; oacc (same memory) goes live
    for (int mt = 0; mt < 4; mt++)
        for (int r = 0; r < 4; r++) {
            int row = mt * 16 + quad * 4 + r;
            float M = fmaxf(fmaxf(sm[0][row], sm[1][row]), fmaxf(sm[2][row], sm[3][row]));
            float L = sl[0][row] * __expf(sm[0][row] - M) + sl[1][row] * __expf(sm[1][row] - M)
                    + sl[2][row] * __expf(sm[2][row] - M) + sl[3][row] * __expf(sm[3][row] - M);
            if (wave == 0 && col == 0) { Mp[wgc * 64 + row] = M; Lp[wgc * 64 + row] = L; }
            float sc = __expf(m_run[mt][r] - M);
            for (int dt = 0; dt < 4; dt++) o_acc[mt][dt][r] *= sc;
        }
    for (int i = tid; i < 64 * 64; i += 256) oacc[i] = 0.f;
    __syncthreads();
    for (int w = 0; w < 4; w++) {
        if (wave == w)
            for (int mt = 0; mt < 4; mt++)
                for (int dt = 0; dt < 4; dt++)
                    for (int r = 0; r < 4; r++)
                        oacc[(mt * 16 + quad * 4 + r) * 64 + dt * 16 + col] += o_acc[mt][dt][r];
        __syncthreads();
    }
    for (int i = tid; i < 64 * 64; i += 256)
        Opart[(size_t)wgc * 4096 + i] = oacc[i];
}

// ---------- 6. merge chunk partials -> AttO (bf16) ----------
__global__ __launch_bounds__(256) void attn_merge(
    const float* __restrict__ Opart, const float* __restrict__ Mp,
    const float* __restrict__ Lp, short* __restrict__ AttO)
{
    int idx = blockIdx.x * 256 + threadIdx.x;  // 128*64*64
    int wg = idx >> 12, rd = idx & 4095, row = rd >> 6, d = rd & 63;
    float M = -__builtin_inff();
    for (int c = 0; c < 8; c++) M = fmaxf(M, Mp[(wg * 8 + c) * 64 + row]);
    float L = 0.f, O = 0.f;
    for (int c = 0; c < 8; c++) {
        float e = __expf(Mp[(wg * 8 + c) * 64 + row] - M);
        L += e * Lp[(wg * 8 + c) * 64 + row];
        O += e * Opart[(size_t)(wg * 8 + c) * 4096 + rd];
    }
    int bt = wg >> 3, h = wg & 7;
    AttO[(size_t)(bt * 64 + row) * 512 + h * 64 + d] = f2bf(O / L);
}

// ---------- launch ----------
extern "C" void kernel_launch(void* const* d_in, const int* in_sizes, int n_in,
                              void* d_out, int out_size, void* d_ws, size_t ws_size,
                              hipStream_t stream)
{
    const float* x   = (const float*)d_in[0];
    const float* lat = (const float*)d_in[1];
    const float* g_x = (const float*)d_in[2];
    const float* b_x = (const float*)d_in[3];
    const float* g_l = (const float*)d_in[4];
    const float* b_l = (const float*)d_in[5];
    const float* Wq  = (const float*)d_in[6];
    const float* Wkv = (const float*)d_in[7];
    const float* Wo  = (const float*)d_in[8];
    float* out = (float*)d_out;

    char* ws = (char*)d_ws;
    size_t off = 0;
    auto alloc = [&](size_t bytes) { char* p = ws + off; off += (bytes + 255) & ~(size_t)255; return p; };
    short* A_kvin = (short*)alloc(33792ull * 1024 * 2);  // 69.2 MB; dead after GEMMs -> reused
    short* Lq     = (short*)alloc(1024ull * 1024 * 2);
    short* WkvT   = (short*)alloc(1024ull * 1024 * 2);
    short* WqT    = (short*)alloc(512ull * 1024 * 2);
    short* WoT    = (short*)alloc(1024ull * 512 * 2);
    short* KVb    = (short*)alloc(33792ull * 1024 * 2);  // 69.2 MB
    short* Qb     = (short*)alloc(1024ull * 512 * 2);
    short* AttO   = (short*)alloc(1024ull * 512 * 2);
    // reuse A_kvin region: Vt = 34.6 MB; partials carved past 36 MiB (17.3 MB used)
    short* Vt    = A_kvin;
    char*  sc2   = (char*)A_kvin + 36ull * 1024 * 1024;
    float* Opart = (float*)sc2;                                   // 16,777,216 B
    float* Mp    = (float*)(sc2 + 16777216);                      // 262,144 B
    float* Lp    = (float*)(sc2 + 16777216 + 262144);             // 262,144 B

    wconv<<<dim3(32, 32), 256, 0, stream>>>(Wkv, WkvT, 1024, 1024, 1.0f);
    wconv<<<dim3(32, 16), 256, 0, stream>>>(Wq,  WqT,  1024, 512,  0.125f);
    wconv<<<dim3(16, 32), 256, 0, stream>>>(Wo,  WoT,  512,  1024, 1.0f);
    ln_kernel<<<8448, 256, 0, stream>>>(x, lat, g_x, b_x, g_l, b_l, A_kvin, Lq);
    // kv GEMM split into two half-M dispatches (diagnostic: exposes any >58us kernel in top-5)
    gemm_bt<short><<<dim3(8, 132), 256, 0, stream>>>(A_kvin, WkvT, KVb, 1024, 1024);
    gemm_bt<short><<<dim3(8, 132), 256, 0, stream>>>(A_kvin + 16896ull * 1024, WkvT,
                                                     KVb + 16896ull * 1024, 1024, 1024);
    gemm_bt<short><<<dim3(4, 8), 256, 0, stream>>>(Lq, WqT, Qb, 512, 1024);
    transpose_v<<<dim3(33, 128), 256, 0, stream>>>(KVb, Vt);
    attn_kernel<<<dim3(128, 8), 256, 0, stream>>>(Qb, KVb, Vt, Opart, Mp, Lp);
    attn_merge<<<2048, 256, 0, stream>>>(Opart, Mp, Lp, AttO);
    gemm_bt<float><<<dim3(8, 8), 256, 0, stream>>>(AttO, WoT, out, 1024, 512);
}

// Round 4
// 388.254 us; speedup vs baseline: 1.1769x; 1.1769x over previous
//
#include <hip/hip_runtime.h>
#include <cstdint>
#include <cstddef>

// ---------- types ----------
typedef __attribute__((ext_vector_type(8))) short short8;   // 8 bf16 (4 VGPRs)
typedef __attribute__((ext_vector_type(4))) short short4v;  // 4 bf16
typedef __attribute__((ext_vector_type(4))) float f32x4;    // MFMA accum

__device__ __forceinline__ short f2bf(float f) {
    union { float f; unsigned u; } c; c.f = f;
    unsigned r = c.u + 0x7fffu + ((c.u >> 16) & 1u);   // RNE
    return (short)(r >> 16);
}

// async global->LDS, 16B per lane; LDS dest must be wave-uniform base + lane*16
__device__ __forceinline__ void gl2lds16(const void* g, void* l) {
    __builtin_amdgcn_global_load_lds(
        (const __attribute__((address_space(1))) void*)g,
        (__attribute__((address_space(3))) void*)l, 16, 0, 0);
}

// ---------- 1. all weight converts in one dispatch (coalesced LDS transpose) ----------
// tiles: [0,1024): Wkv 32x32 ktiles x ntiles; [1024,1536): Wq (32x16); [1536,2048): Wo (16x32)
__global__ __launch_bounds__(256) void wconv_all(
    const float* __restrict__ Wq, const float* __restrict__ Wkv, const float* __restrict__ Wo,
    short* __restrict__ WqT, short* __restrict__ WkvT, short* __restrict__ WoT)
{
    __shared__ float t[32][33];
    const int id = blockIdx.x;
    const float* S; short* D; int K, N, kt, nt; float scale = 1.0f;
    if (id < 1024)      { S = Wkv; D = WkvT; K = 1024; N = 1024; kt = (id >> 5) * 32;          nt = (id & 31) * 32; }
    else if (id < 1536) { S = Wq;  D = WqT;  K = 1024; N = 512;  kt = ((id - 1024) >> 4) * 32; nt = ((id - 1024) & 15) * 32; scale = 0.125f; }
    else                { S = Wo;  D = WoT;  K = 512;  N = 1024; kt = ((id - 1536) >> 5) * 32; nt = ((id - 1536) & 31) * 32; }
    const int x = threadIdx.x & 31, y4 = (threadIdx.x >> 5) * 4;
    for (int i = 0; i < 4; i++)
        t[y4 + i][x] = S[(size_t)(kt + y4 + i) * N + nt + x];
    __syncthreads();
    for (int i = 0; i < 4; i++)
        D[(size_t)(nt + y4 + i) * K + kt + x] = f2bf(t[x][y4 + i] * scale);
}

// ---------- 2. LayerNorm -> bf16, one WAVE per row (no barriers, no LDS) ----------
__global__ __launch_bounds__(256) void ln_kernel(
    const float* __restrict__ x, const float* __restrict__ lat,
    const float* __restrict__ gx, const float* __restrict__ bx,
    const float* __restrict__ gl, const float* __restrict__ bl,
    short* __restrict__ Aout, short* __restrict__ Lq)
{
    const int wave = threadIdx.x >> 6, lane = threadIdx.x & 63;
    const int r = blockIdx.x * 4 + wave;   // 0..33791
    const float *src, *g, *b; size_t drow; short* dst2 = nullptr;
    if (r < 32768) {
        int bt = r >> 11, i = r & 2047;
        src = x + (size_t)r * 1024; g = gx; b = bx;
        drow = (size_t)bt * 2112 + i;
    } else {
        int idx = r - 32768;
        int bt = idx >> 6, i = idx & 63;
        src = lat + (size_t)idx * 1024; g = gl; b = bl;
        drow = (size_t)bt * 2112 + 2048 + i;
        dst2 = Lq + (size_t)idx * 1024;
    }
    float4 v[4];
    for (int j = 0; j < 4; j++) v[j] = ((const float4*)src)[lane + 64 * j];
    float s = 0.f, s2 = 0.f;
    for (int j = 0; j < 4; j++) {
        s  += v[j].x + v[j].y + v[j].z + v[j].w;
        s2 += v[j].x * v[j].x + v[j].y * v[j].y + v[j].z * v[j].z + v[j].w * v[j].w;
    }
    for (int off = 32; off >= 1; off >>= 1) { s += __shfl_xor(s, off); s2 += __shfl_xor(s2, off); }
    const float mu   = s * (1.f / 1024.f);
    const float rstd = rsqrtf(s2 * (1.f / 1024.f) - mu * mu + 1e-5f);
    for (int j = 0; j < 4; j++) {
        float4 gv = ((const float4*)g)[lane + 64 * j];
        float4 bv = ((const float4*)b)[lane + 64 * j];
        short4v o;
        o[0] = f2bf((v[j].x - mu) * rstd * gv.x + bv.x);
        o[1] = f2bf((v[j].y - mu) * rstd * gv.y + bv.y);
        o[2] = f2bf((v[j].z - mu) * rstd * gv.z + bv.z);
        o[3] = f2bf((v[j].w - mu) * rstd * gv.w + bv.w);
        *(short4v*)(Aout + drow * 1024 + (size_t)(lane + 64 * j) * 4) = o;
        if (dst2) *(short4v*)(dst2 + (size_t)(lane + 64 * j) * 4) = o;
    }
}

// ---------- 3a. fused kv+q GEMM, K=1024; grid (268, 8), x = m-tile FASTEST ----------
// x<264: kv tile (m0=x*128, n0=y*128). x>=264: q tile, extra=(x-264)*8+y in [0,32):
//   qm = extra>>2, qn = extra&3.  (x=m-fastest: linear%8 spreads m-tiles over XCDs,
//   each XCD keeps the 2MB B panel L2-resident and reads 1/8 of A — round-2 proven.)
__global__ __launch_bounds__(256) void gemm_kvq(
    const short* __restrict__ A, const short* __restrict__ Bt, short* __restrict__ C,
    const short* __restrict__ Aq, const short* __restrict__ Btq, short* __restrict__ Cq)
{
    __shared__ short As[128 * 32];
    __shared__ short Bs[128 * 32];
    const int tid  = threadIdx.x;
    const int wave = tid >> 6, lane = tid & 63;
    const int col  = lane & 15, quad = lane >> 4;
    const short *pA, *pB; short* pC; int m0, n0, N;
    if (blockIdx.x < 264) {
        pA = A; pB = Bt; pC = C; N = 1024;
        m0 = blockIdx.x * 128; n0 = blockIdx.y * 128;
    } else {
        int extra = (blockIdx.x - 264) * 8 + blockIdx.y;
        pA = Aq; pB = Btq; pC = Cq; N = 512;
        m0 = (extra >> 2) * 128; n0 = (extra & 3) * 128;
    }
    const int K = 1024;
    const int wm = (wave >> 1) * 64, wn = (wave & 1) * 64;
    const int sr = tid >> 2;           // staging row 0..63
    const int sk = (tid & 3) * 8;      // staging k offset

    f32x4 acc[4][4];
    for (int i = 0; i < 4; i++) for (int j = 0; j < 4; j++) acc[i][j] = f32x4{0.f, 0.f, 0.f, 0.f};

    const short* Ar0 = pA + (size_t)(m0 + sr)      * K + sk;
    const short* Ar1 = pA + (size_t)(m0 + sr + 64) * K + sk;
    const short* Br0 = pB + (size_t)(n0 + sr)      * K + sk;
    const short* Br1 = pB + (size_t)(n0 + sr + 64) * K + sk;
    short* lA0 = &As[sr * 32 + sk];
    short* lA1 = &As[(sr + 64) * 32 + sk];
    short* lB0 = &Bs[sr * 32 + sk];
    short* lB1 = &Bs[(sr + 64) * 32 + sk];

    for (int k0 = 0; k0 < K; k0 += 32) {
        __syncthreads();
        gl2lds16(Ar0 + k0, lA0);
        gl2lds16(Ar1 + k0, lA1);
        gl2lds16(Br0 + k0, lB0);
        gl2lds16(Br1 + k0, lB1);
        __syncthreads();
        short8 af[4], bf[4];
        for (int mt = 0; mt < 4; mt++) af[mt] = *(const short8*)&As[(wm + mt * 16 + col) * 32 + quad * 8];
        for (int nt = 0; nt < 4; nt++) bf[nt] = *(const short8*)&Bs[(wn + nt * 16 + col) * 32 + quad * 8];
        for (int mt = 0; mt < 4; mt++)
            for (int nt = 0; nt < 4; nt++)
                acc[mt][nt] = __builtin_amdgcn_mfma_f32_16x16x32_bf16(af[mt], bf[nt], acc[mt][nt], 0, 0, 0);
    }
    for (int mt = 0; mt < 4; mt++)
        for (int nt = 0; nt < 4; nt++)
            for (int r = 0; r < 4; r++) {
                int row = m0 + wm + mt * 16 + quad * 4 + r;
                int cc  = n0 + wn + nt * 16 + col;
                pC[(size_t)row * N + cc] = f2bf(acc[mt][nt][r]);
            }
}

// ---------- 3b. generic bf16 GEMM (for the out projection), x = m-tile ----------
template <typename OutT>
__global__ __launch_bounds__(256) void gemm_bt(
    const short* __restrict__ A, const short* __restrict__ Bt,
    OutT* __restrict__ C, int N, int K)
{
    __shared__ short As[128 * 32];
    __shared__ short Bs[128 * 32];
    const int tid  = threadIdx.x;
    const int wave = tid >> 6, lane = tid & 63;
    const int col  = lane & 15, quad = lane >> 4;
    const int m0 = blockIdx.x * 128, n0 = blockIdx.y * 128;
    const int wm = (wave >> 1) * 64, wn = (wave & 1) * 64;
    const int sr = tid >> 2;
    const int sk = (tid & 3) * 8;

    f32x4 acc[4][4];
    for (int i = 0; i < 4; i++) for (int j = 0; j < 4; j++) acc[i][j] = f32x4{0.f, 0.f, 0.f, 0.f};

    const short* Ar0 = A  + (size_t)(m0 + sr)      * K + sk;
    const short* Ar1 = A  + (size_t)(m0 + sr + 64) * K + sk;
    const short* Br0 = Bt + (size_t)(n0 + sr)      * K + sk;
    const short* Br1 = Bt + (size_t)(n0 + sr + 64) * K + sk;
    short* lA0 = &As[sr * 32 + sk];
    short* lA1 = &As[(sr + 64) * 32 + sk];
    short* lB0 = &Bs[sr * 32 + sk];
    short* lB1 = &Bs[(sr + 64) * 32 + sk];

    for (int k0 = 0; k0 < K; k0 += 32) {
        __syncthreads();
        gl2lds16(Ar0 + k0, lA0);
        gl2lds16(Ar1 + k0, lA1);
        gl2lds16(Br0 + k0, lB0);
        gl2lds16(Br1 + k0, lB1);
        __syncthreads();
        short8 af[4], bf[4];
        for (int mt = 0; mt < 4; mt++) af[mt] = *(const short8*)&As[(wm + mt * 16 + col) * 32 + quad * 8];
        for (int nt = 0; nt < 4; nt++) bf[nt] = *(const short8*)&Bs[(wn + nt * 16 + col) * 32 + quad * 8];
        for (int mt = 0; mt < 4; mt++)
            for (int nt = 0; nt < 4; nt++)
                acc[mt][nt] = __builtin_amdgcn_mfma_f32_16x16x32_bf16(af[mt], bf[nt], acc[mt][nt], 0, 0, 0);
    }
    for (int mt = 0; mt < 4; mt++)
        for (int nt = 0; nt < 4; nt++)
            for (int r = 0; r < 4; r++) {
                int row = m0 + wm + mt * 16 + quad * 4 + r;
                int cc  = n0 + wn + nt * 16 + col;
                float v = acc[mt][nt][r];
                if constexpr (sizeof(OutT) == 2) C[(size_t)row * N + cc] = (OutT)f2bf(v);
                else                             C[(size_t)row * N + cc] = v;
            }
}

// ---------- 4. transpose V: KV[bt*2112+j][512+h*64+d] -> Vt[(bt*8+h)*64+d][j] ----------
__global__ __launch_bounds__(256) void transpose_v(const short* __restrict__ KV, short* __restrict__ Vt)
{
    __shared__ short tile[64 * 68];
    const int bth = blockIdx.y, bt = bth >> 3, h = bth & 7;
    const int jt = blockIdx.x * 64;
    const int tid = threadIdx.x;
    for (int it = 0; it < 2; ++it) {
        int s = tid + it * 256;
        int j = s >> 3, dv = (s & 7) * 8;
        short8 v = *(const short8*)(KV + (size_t)(bt * 2112 + jt + j) * 1024 + 512 + h * 64 + dv);
        short4v lo = {v[0], v[1], v[2], v[3]}, hi = {v[4], v[5], v[6], v[7]};
        *(short4v*)&tile[j * 68 + dv]     = lo;
        *(short4v*)&tile[j * 68 + dv + 4] = hi;
    }
    __syncthreads();
    for (int it = 0; it < 2; ++it) {
        int s = tid + it * 256;
        int d = s >> 3, jv = (s & 7) * 8;
        short8 o;
        for (int jj = 0; jj < 8; jj++) o[jj] = tile[(jv + jj) * 68 + d];
        *(short8*)(Vt + (size_t)(bth * 64 + d) * 2112 + jt + jv) = o;
    }
}

// ---------- 5. attention: grid (128 wg, 4 chunks); un-normalized partials ----------
__global__ __launch_bounds__(256) void attn_kernel(
    const short* __restrict__ Q,    // (1024, 512)
    const short* __restrict__ KV,   // (33792, 1024) k in cols 0..511
    const short* __restrict__ Vt,   // (128*64, 2112)
    float* __restrict__ Opart,      // (512, 64, 64)
    float* __restrict__ Mp,         // (512, 64)
    float* __restrict__ Lp)         // (512, 64)
{
    __shared__ __align__(16) short p_lds[4][64 * 72];   // 36.9 KB; oacc overlays after loop
    __shared__ float sm[4][64];
    __shared__ float sl[4][64];
    float* oacc = (float*)&p_lds[0][0];                 // 16 KB, lifetime-disjoint

    const int wg = blockIdx.x;            // 0..127 = bt*8 + h
    const int ck = blockIdx.y;            // chunk 0..3
    const int wgc = wg * 4 + ck;
    const int bt = wg >> 3, h = wg & 7;
    const int tid = threadIdx.x;
    const int wave = tid >> 6, lane = tid & 63;
    const int col = lane & 15, quad = lane >> 4;

    short8 qf[4][2];
    for (int mt = 0; mt < 4; mt++)
        for (int ks = 0; ks < 2; ks++)
            qf[mt][ks] = *(const short8*)(Q + (size_t)(bt * 64 + mt * 16 + col) * 512
                                            + h * 64 + ks * 32 + quad * 8);

    float m_run[4][4], l_run[4][4];
    f32x4 o_acc[4][4];
    for (int mt = 0; mt < 4; mt++)
        for (int r = 0; r < 4; r++) { m_run[mt][r] = -__builtin_inff(); l_run[mt][r] = 0.f; }
    for (int mt = 0; mt < 4; mt++)
        for (int dt = 0; dt < 4; dt++) o_acc[mt][dt] = f32x4{0.f, 0.f, 0.f, 0.f};

    short* pl = p_lds[wave];

    // 33 key-blocks over 16 (chunk,wave) pairs: pair p handles jb = p, p+16 (+32 for p=0)
    for (int jb = ck * 4 + wave; jb < 33; jb += 16) {
        f32x4 s[4][4];
        for (int mt = 0; mt < 4; mt++) for (int nt = 0; nt < 4; nt++) s[mt][nt] = f32x4{0.f, 0.f, 0.f, 0.f};
        for (int nt = 0; nt < 4; nt++) {
            const int j = jb * 64 + nt * 16 + col;
            const short* kp = KV + (size_t)(bt * 2112 + j) * 1024 + h * 64 + quad * 8;
            short8 k0 = *(const short8*)kp;
            short8 k1 = *(const short8*)(kp + 32);
            for (int mt = 0; mt < 4; mt++) {
                s[mt][nt] = __builtin_amdgcn_mfma_f32_16x16x32_bf16(qf[mt][0], k0, s[mt][nt], 0, 0, 0);
                s[mt][nt] = __builtin_amdgcn_mfma_f32_16x16x32_bf16(qf[mt][1], k1, s[mt][nt], 0, 0, 0);
            }
        }
        for (int mt = 0; mt < 4; mt++)
            for (int r = 0; r < 4; r++) {
                float mx = fmaxf(fmaxf(s[mt][0][r], s[mt][1][r]), fmaxf(s[mt][2][r], s[mt][3][r]));
                for (int off = 8; off >= 1; off >>= 1) mx = fmaxf(mx, __shfl_xor(mx, off));
                float mnew = fmaxf(m_run[mt][r], mx);
                float alpha = __expf(m_run[mt][r] - mnew);
                float rs = 0.f;
                for (int nt = 0; nt < 4; nt++) {
                    float p = __expf(s[mt][nt][r] - mnew);
                    s[mt][nt][r] = p;
                    rs += p;
                }
                for (int off = 8; off >= 1; off >>= 1) rs += __shfl_xor(rs, off);
                m_run[mt][r] = mnew;
                l_run[mt][r] = l_run[mt][r] * alpha + rs;
                for (int dt = 0; dt < 4; dt++) o_acc[mt][dt][r] *= alpha;
            }
        for (int mt = 0; mt < 4; mt++)
            for (int nt = 0; nt < 4; nt++)
                for (int r = 0; r < 4; r++)
                    pl[(mt * 16 + quad * 4 + r) * 72 + nt * 16 + col] = f2bf(s[mt][nt][r]);
        for (int ks = 0; ks < 2; ks++) {
            short8 vf[4];
            for (int dt = 0; dt < 4; dt++)
                vf[dt] = *(const short8*)(Vt + (size_t)(wg * 64 + dt * 16 + col) * 2112
                                             + jb * 64 + ks * 32 + quad * 8);
            for (int mt = 0; mt < 4; mt++) {
                short8 pf = *(const short8*)(pl + (mt * 16 + col) * 72 + ks * 32 + quad * 8);
                for (int dt = 0; dt < 4; dt++)
                    o_acc[mt][dt] = __builtin_amdgcn_mfma_f32_16x16x32_bf16(pf, vf[dt], o_acc[mt][dt], 0, 0, 0);
            }
        }
    }

    // ---- merge 4 waves; emit UN-normalized partial (O~, M, L) for this chunk ----
    if (col == 0)
        for (int mt = 0; mt < 4; mt++)
            for (int r = 0; r < 4; r++) {
                int row = mt * 16 + quad * 4 + r;
                sm[wave][row] = m_run[mt][r];
                sl[wave][row] = l_run[mt][r];
            }
    __syncthreads();     // p_lds dead after this; oacc (same memory) goes live
    for (int mt = 0; mt < 4; mt++)
        for (int r = 0; r < 4; r++) {
            int row = mt * 16 + quad * 4 + r;
            float M = fmaxf(fmaxf(sm[0][row], sm[1][row]), fmaxf(sm[2][row], sm[3][row]));
            float L = sl[0][row] * __expf(sm[0][row] - M) + sl[1][row] * __expf(sm[1][row] - M)
                    + sl[2][row] * __expf(sm[2][row] - M) + sl[3][row] * __expf(sm[3][row] - M);
            if (wave == 0 && col == 0) { Mp[wgc * 64 + row] = M; Lp[wgc * 64 + row] = L; }
            float sc = __expf(m_run[mt][r] - M);
            for (int dt = 0; dt < 4; dt++) o_acc[mt][dt][r] *= sc;
        }
    for (int i = tid; i < 64 * 64; i += 256) oacc[i] = 0.f;
    __syncthreads();
    for (int w = 0; w < 4; w++) {
        if (wave == w)
            for (int mt = 0; mt < 4; mt++)
                for (int dt = 0; dt < 4; dt++)
                    for (int r = 0; r < 4; r++)
                        oacc[(mt * 16 + quad * 4 + r) * 64 + dt * 16 + col] += o_acc[mt][dt][r];
        __syncthreads();
    }
    for (int i = tid; i < 64 * 64; i += 256)
        Opart[(size_t)wgc * 4096 + i] = oacc[i];
}

// ---------- 6. merge chunk partials -> AttO (bf16) ----------
__global__ __launch_bounds__(256) void attn_merge(
    const float* __restrict__ Opart, const float* __restrict__ Mp,
    const float* __restrict__ Lp, short* __restrict__ AttO)
{
    int idx = blockIdx.x * 256 + threadIdx.x;  // 128*64*64
    int wg = idx >> 12, rd = idx & 4095, row = rd >> 6, d = rd & 63;
    float M = -__builtin_inff();
    for (int c = 0; c < 4; c++) M = fmaxf(M, Mp[(wg * 4 + c) * 64 + row]);
    float L = 0.f, O = 0.f;
    for (int c = 0; c < 4; c++) {
        float e = __expf(Mp[(wg * 4 + c) * 64 + row] - M);
        L += e * Lp[(wg * 4 + c) * 64 + row];
        O += e * Opart[(size_t)(wg * 4 + c) * 4096 + rd];
    }
    int bt = wg >> 3, h = wg & 7;
    AttO[(size_t)(bt * 64 + row) * 512 + h * 64 + d] = f2bf(O / L);
}

// ---------- launch ----------
extern "C" void kernel_launch(void* const* d_in, const int* in_sizes, int n_in,
                              void* d_out, int out_size, void* d_ws, size_t ws_size,
                              hipStream_t stream)
{
    const float* x   = (const float*)d_in[0];
    const float* lat = (const float*)d_in[1];
    const float* g_x = (const float*)d_in[2];
    const float* b_x = (const float*)d_in[3];
    const float* g_l = (const float*)d_in[4];
    const float* b_l = (const float*)d_in[5];
    const float* Wq  = (const float*)d_in[6];
    const float* Wkv = (const float*)d_in[7];
    const float* Wo  = (const float*)d_in[8];
    float* out = (float*)d_out;

    char* ws = (char*)d_ws;
    size_t off = 0;
    auto alloc = [&](size_t bytes) { char* p = ws + off; off += (bytes + 255) & ~(size_t)255; return p; };
    short* A_kvin = (short*)alloc(33792ull * 1024 * 2);  // 69.2 MB; dead after GEMMs -> reused
    short* Lq     = (short*)alloc(1024ull * 1024 * 2);
    short* WkvT   = (short*)alloc(1024ull * 1024 * 2);
    short* WqT    = (short*)alloc(512ull * 1024 * 2);
    short* WoT    = (short*)alloc(1024ull * 512 * 2);
    short* KVb    = (short*)alloc(33792ull * 1024 * 2);  // 69.2 MB
    short* Qb     = (short*)alloc(1024ull * 512 * 2);
    short* AttO   = (short*)alloc(1024ull * 512 * 2);
    // reuse A_kvin region: Vt = 34.6 MB; partials carved past 36 MiB mark
    short* Vt    = A_kvin;
    char*  sc2   = (char*)A_kvin + 36ull * 1024 * 1024;
    float* Opart = (float*)sc2;                       // 8,388,608 B
    float* Mp    = (float*)(sc2 + 8388608);           // 131,072 B
    float* Lp    = (float*)(sc2 + 8388608 + 131072);  // 131,072 B

    wconv_all<<<2048, 256, 0, stream>>>(Wq, Wkv, Wo, WqT, WkvT, WoT);
    ln_kernel<<<8448, 256, 0, stream>>>(x, lat, g_x, b_x, g_l, b_l, A_kvin, Lq);
    gemm_kvq<<<dim3(268, 8), 256, 0, stream>>>(A_kvin, WkvT, KVb, Lq, WqT, Qb);
    transpose_v<<<dim3(33, 128), 256, 0, stream>>>(KVb, Vt);
    attn_kernel<<<dim3(128, 4), 256, 0, stream>>>(Qb, KVb, Vt, Opart, Mp, Lp);
    attn_merge<<<2048, 256, 0, stream>>>(Opart, Mp, Lp, AttO);
    gemm_bt<float><<<dim3(8, 8), 256, 0, stream>>>(AttO, WoT, out, 1024, 512);
}

// Round 5
// 385.061 us; speedup vs baseline: 1.1866x; 1.0083x over previous
//
#include <hip/hip_runtime.h>
#include <cstdint>
#include <cstddef>

// ---------- types ----------
typedef __attribute__((ext_vector_type(8))) short short8;   // 8 bf16 (4 VGPRs)
typedef __attribute__((ext_vector_type(4))) short short4v;  // 4 bf16
typedef __attribute__((ext_vector_type(4))) float f32x4;    // MFMA accum

__device__ __forceinline__ short f2bf(float f) {
    union { float f; unsigned u; } c; c.f = f;
    unsigned r = c.u + 0x7fffu + ((c.u >> 16) & 1u);   // RNE
    return (short)(r >> 16);
}

// async global->LDS, 16B per lane; LDS dest must be wave-uniform base + lane*16
__device__ __forceinline__ void gl2lds16(const void* g, void* l) {
    __builtin_amdgcn_global_load_lds(
        (const __attribute__((address_space(1))) void*)g,
        (__attribute__((address_space(3))) void*)l, 16, 0, 0);
}

// ---------- 1. prep: LayerNorm (blocks 0..8447) + weight transposes (8448..10495) ----------
__global__ __launch_bounds__(256) void prep_kernel(
    const float* __restrict__ x, const float* __restrict__ lat,
    const float* __restrict__ gx, const float* __restrict__ bx,
    const float* __restrict__ gl, const float* __restrict__ bl,
    short* __restrict__ Aout, short* __restrict__ Lq,
    const float* __restrict__ Wq, const float* __restrict__ Wkv, const float* __restrict__ Wo,
    short* __restrict__ WqT, short* __restrict__ WkvT, short* __restrict__ WoT)
{
    __shared__ float t[32][33];
    if (blockIdx.x < 8448) {
        // ---- LayerNorm, one wave per row ----
        const int wave = threadIdx.x >> 6, lane = threadIdx.x & 63;
        const int r = blockIdx.x * 4 + wave;   // 0..33791
        const float *src, *g, *b; size_t drow; short* dst2 = nullptr;
        if (r < 32768) {
            int bt = r >> 11, i = r & 2047;
            src = x + (size_t)r * 1024; g = gx; b = bx;
            drow = (size_t)bt * 2112 + i;
        } else {
            int idx = r - 32768;
            int bt = idx >> 6, i = idx & 63;
            src = lat + (size_t)idx * 1024; g = gl; b = bl;
            drow = (size_t)bt * 2112 + 2048 + i;
            dst2 = Lq + (size_t)idx * 1024;
        }
        float4 v[4];
        for (int j = 0; j < 4; j++) v[j] = ((const float4*)src)[lane + 64 * j];
        float s = 0.f, s2 = 0.f;
        for (int j = 0; j < 4; j++) {
            s  += v[j].x + v[j].y + v[j].z + v[j].w;
            s2 += v[j].x * v[j].x + v[j].y * v[j].y + v[j].z * v[j].z + v[j].w * v[j].w;
        }
        for (int off = 32; off >= 1; off >>= 1) { s += __shfl_xor(s, off); s2 += __shfl_xor(s2, off); }
        const float mu   = s * (1.f / 1024.f);
        const float rstd = rsqrtf(s2 * (1.f / 1024.f) - mu * mu + 1e-5f);
        for (int j = 0; j < 4; j++) {
            float4 gv = ((const float4*)g)[lane + 64 * j];
            float4 bv = ((const float4*)b)[lane + 64 * j];
            short4v o;
            o[0] = f2bf((v[j].x - mu) * rstd * gv.x + bv.x);
            o[1] = f2bf((v[j].y - mu) * rstd * gv.y + bv.y);
            o[2] = f2bf((v[j].z - mu) * rstd * gv.z + bv.z);
            o[3] = f2bf((v[j].w - mu) * rstd * gv.w + bv.w);
            *(short4v*)(Aout + drow * 1024 + (size_t)(lane + 64 * j) * 4) = o;
            if (dst2) *(short4v*)(dst2 + (size_t)(lane + 64 * j) * 4) = o;
        }
    } else {
        // ---- weight transpose via LDS tile ----
        const int id = blockIdx.x - 8448;
        const float* S; short* D; int K, N, kt, nt; float scale = 1.0f;
        if (id < 1024)      { S = Wkv; D = WkvT; K = 1024; N = 1024; kt = (id >> 5) * 32;          nt = (id & 31) * 32; }
        else if (id < 1536) { S = Wq;  D = WqT;  K = 1024; N = 512;  kt = ((id - 1024) >> 4) * 32; nt = ((id - 1024) & 15) * 32; scale = 0.125f; }
        else                { S = Wo;  D = WoT;  K = 512;  N = 1024; kt = ((id - 1536) >> 5) * 32; nt = ((id - 1536) & 31) * 32; }
        const int xx = threadIdx.x & 31, y4 = (threadIdx.x >> 5) * 4;
        for (int i = 0; i < 4; i++)
            t[y4 + i][xx] = S[(size_t)(kt + y4 + i) * N + nt + xx];
        __syncthreads();
        for (int i = 0; i < 4; i++)
            D[(size_t)(nt + y4 + i) * K + kt + xx] = f2bf(t[xx][y4 + i] * scale);
    }
}

// ---------- 2. fused kv+q GEMM, K=1024, BK=64 as 2 sub-tiles (half the barriers) ----
// grid (268, 8), x = m-tile FASTEST (linear%8 -> XCD = m-group; B stays L2-resident).
// x<264: kv tile. Epilogue: n<512 -> Kb (512-wide); n>=512 -> Vt transposed.
// x>=264: q tile, extra=(x-264)*8+y in [0,32): qm=extra>>2, qn=extra&3 -> Qb.
__global__ __launch_bounds__(256) void gemm_kvq(
    const short* __restrict__ A, const short* __restrict__ Bt,
    short* __restrict__ Kb, short* __restrict__ Vt,
    const short* __restrict__ Aq, const short* __restrict__ Btq, short* __restrict__ Qb)
{
    __shared__ short As0[128 * 32], As1[128 * 32];
    __shared__ short Bs0[128 * 32], Bs1[128 * 32];
    const int tid  = threadIdx.x;
    const int wave = tid >> 6, lane = tid & 63;
    const int col  = lane & 15, quad = lane >> 4;
    const short *pA, *pB; int m0, n0, kvmode;
    if (blockIdx.x < 264) {
        pA = A; pB = Bt; kvmode = 1;
        m0 = blockIdx.x * 128; n0 = blockIdx.y * 128;
    } else {
        int extra = (blockIdx.x - 264) * 8 + blockIdx.y;
        pA = Aq; pB = Btq; kvmode = 0;
        m0 = (extra >> 2) * 128; n0 = (extra & 3) * 128;
    }
    const int K = 1024;
    const int wm = (wave >> 1) * 64, wn = (wave & 1) * 64;
    const int sr = tid >> 2;           // staging row 0..63
    const int sk = (tid & 3) * 8;      // staging k offset (shorts)

    f32x4 acc[4][4];
    for (int i = 0; i < 4; i++) for (int j = 0; j < 4; j++) acc[i][j] = f32x4{0.f, 0.f, 0.f, 0.f};

    const short* Ar0 = pA + (size_t)(m0 + sr)      * K + sk;
    const short* Ar1 = pA + (size_t)(m0 + sr + 64) * K + sk;
    const short* Br0 = pB + (size_t)(n0 + sr)      * K + sk;
    const short* Br1 = pB + (size_t)(n0 + sr + 64) * K + sk;
    short* lA0 = &As0[sr * 32 + sk];  short* lA1 = &As0[(sr + 64) * 32 + sk];
    short* lA2 = &As1[sr * 32 + sk];  short* lA3 = &As1[(sr + 64) * 32 + sk];
    short* lB0 = &Bs0[sr * 32 + sk];  short* lB1 = &Bs0[(sr + 64) * 32 + sk];
    short* lB2 = &Bs1[sr * 32 + sk];  short* lB3 = &Bs1[(sr + 64) * 32 + sk];

    for (int k0 = 0; k0 < K; k0 += 64) {
        __syncthreads();
        gl2lds16(Ar0 + k0, lA0);      gl2lds16(Ar1 + k0, lA1);
        gl2lds16(Ar0 + k0 + 32, lA2); gl2lds16(Ar1 + k0 + 32, lA3);
        gl2lds16(Br0 + k0, lB0);      gl2lds16(Br1 + k0, lB1);
        gl2lds16(Br0 + k0 + 32, lB2); gl2lds16(Br1 + k0 + 32, lB3);
        __syncthreads();
        {
            short8 af[4], bf[4];
            for (int mt = 0; mt < 4; mt++) af[mt] = *(const short8*)&As0[(wm + mt * 16 + col) * 32 + quad * 8];
            for (int nt = 0; nt < 4; nt++) bf[nt] = *(const short8*)&Bs0[(wn + nt * 16 + col) * 32 + quad * 8];
            for (int mt = 0; mt < 4; mt++)
                for (int nt = 0; nt < 4; nt++)
                    acc[mt][nt] = __builtin_amdgcn_mfma_f32_16x16x32_bf16(af[mt], bf[nt], acc[mt][nt], 0, 0, 0);
        }
        {
            short8 af[4], bf[4];
            for (int mt = 0; mt < 4; mt++) af[mt] = *(const short8*)&As1[(wm + mt * 16 + col) * 32 + quad * 8];
            for (int nt = 0; nt < 4; nt++) bf[nt] = *(const short8*)&Bs1[(wn + nt * 16 + col) * 32 + quad * 8];
            for (int mt = 0; mt < 4; mt++)
                for (int nt = 0; nt < 4; nt++)
                    acc[mt][nt] = __builtin_amdgcn_mfma_f32_16x16x32_bf16(af[mt], bf[nt], acc[mt][nt], 0, 0, 0);
        }
    }
    if (kvmode) {
        for (int mt = 0; mt < 4; mt++)
            for (int nt = 0; nt < 4; nt++) {
                int ng = n0 + wn + nt * 16 + col;
                int base_m = m0 + wm + mt * 16 + quad * 4;
                if (ng < 512) {
                    for (int r = 0; r < 4; r++)
                        Kb[(size_t)(base_m + r) * 512 + ng] = f2bf(acc[mt][nt][r]);
                } else {
                    int nv = ng - 512, h = nv >> 6, d = nv & 63;
                    int bt = base_m / 2112, j = base_m - bt * 2112;  // 4-row group never straddles bt
                    short4v pk;
                    for (int r = 0; r < 4; r++) pk[r] = f2bf(acc[mt][nt][r]);
                    *(short4v*)&Vt[(size_t)((bt * 8 + h) * 64 + d) * 2112 + j] = pk;
                }
            }
    } else {
        for (int mt = 0; mt < 4; mt++)
            for (int nt = 0; nt < 4; nt++)
                for (int r = 0; r < 4; r++) {
                    int row = m0 + wm + mt * 16 + quad * 4 + r;
                    int cc  = n0 + wn + nt * 16 + col;
                    Qb[(size_t)row * 512 + cc] = f2bf(acc[mt][nt][r]);
                }
    }
}

// ---------- 3. out-projection GEMM, K=512, BK=64 x2 sub-tiles, fp32 out ----------
__global__ __launch_bounds__(256) void gemm_out(
    const short* __restrict__ A, const short* __restrict__ Bt, float* __restrict__ C)
{
    __shared__ short As0[128 * 32], As1[128 * 32];
    __shared__ short Bs0[128 * 32], Bs1[128 * 32];
    const int tid  = threadIdx.x;
    const int wave = tid >> 6, lane = tid & 63;
    const int col  = lane & 15, quad = lane >> 4;
    const int m0 = blockIdx.x * 128, n0 = blockIdx.y * 128;
    const int K = 512, N = 1024;
    const int wm = (wave >> 1) * 64, wn = (wave & 1) * 64;
    const int sr = tid >> 2, sk = (tid & 3) * 8;

    f32x4 acc[4][4];
    for (int i = 0; i < 4; i++) for (int j = 0; j < 4; j++) acc[i][j] = f32x4{0.f, 0.f, 0.f, 0.f};

    const short* Ar0 = A  + (size_t)(m0 + sr)      * K + sk;
    const short* Ar1 = A  + (size_t)(m0 + sr + 64) * K + sk;
    const short* Br0 = Bt + (size_t)(n0 + sr)      * K + sk;
    const short* Br1 = Bt + (size_t)(n0 + sr + 64) * K + sk;
    short* lA0 = &As0[sr * 32 + sk];  short* lA1 = &As0[(sr + 64) * 32 + sk];
    short* lA2 = &As1[sr * 32 + sk];  short* lA3 = &As1[(sr + 64) * 32 + sk];
    short* lB0 = &Bs0[sr * 32 + sk];  short* lB1 = &Bs0[(sr + 64) * 32 + sk];
    short* lB2 = &Bs1[sr * 32 + sk];  short* lB3 = &Bs1[(sr + 64) * 32 + sk];

    for (int k0 = 0; k0 < K; k0 += 64) {
        __syncthreads();
        gl2lds16(Ar0 + k0, lA0);      gl2lds16(Ar1 + k0, lA1);
        gl2lds16(Ar0 + k0 + 32, lA2); gl2lds16(Ar1 + k0 + 32, lA3);
        gl2lds16(Br0 + k0, lB0);      gl2lds16(Br1 + k0, lB1);
        gl2lds16(Br0 + k0 + 32, lB2); gl2lds16(Br1 + k0 + 32, lB3);
        __syncthreads();
        {
            short8 af[4], bf[4];
            for (int mt = 0; mt < 4; mt++) af[mt] = *(const short8*)&As0[(wm + mt * 16 + col) * 32 + quad * 8];
            for (int nt = 0; nt < 4; nt++) bf[nt] = *(const short8*)&Bs0[(wn + nt * 16 + col) * 32 + quad * 8];
            for (int mt = 0; mt < 4; mt++)
                for (int nt = 0; nt < 4; nt++)
                    acc[mt][nt] = __builtin_amdgcn_mfma_f32_16x16x32_bf16(af[mt], bf[nt], acc[mt][nt], 0, 0, 0);
        }
        {
            short8 af[4], bf[4];
            for (int mt = 0; mt < 4; mt++) af[mt] = *(const short8*)&As1[(wm + mt * 16 + col) * 32 + quad * 8];
            for (int nt = 0; nt < 4; nt++) bf[nt] = *(const short8*)&Bs1[(wn + nt * 16 + col) * 32 + quad * 8];
            for (int mt = 0; mt < 4; mt++)
                for (int nt = 0; nt < 4; nt++)
                    acc[mt][nt] = __builtin_amdgcn_mfma_f32_16x16x32_bf16(af[mt], bf[nt], acc[mt][nt], 0, 0, 0);
        }
    }
    for (int mt = 0; mt < 4; mt++)
        for (int nt = 0; nt < 4; nt++)
            for (int r = 0; r < 4; r++) {
                int row = m0 + wm + mt * 16 + quad * 4 + r;
                int cc  = n0 + wn + nt * 16 + col;
                C[(size_t)row * N + cc] = acc[mt][nt][r];
            }
}

// ---------- 4. attention: grid (128 wg, 4 chunks); un-normalized partials ----------
__global__ __launch_bounds__(256) void attn_kernel(
    const short* __restrict__ Q,    // (1024, 512)
    const short* __restrict__ Kb,   // (33792, 512)
    const short* __restrict__ Vt,   // (128*64, 2112)
    float* __restrict__ Opart,      // (512, 64, 64)
    float* __restrict__ Mp,         // (512, 64)
    float* __restrict__ Lp)         // (512, 64)
{
    __shared__ __align__(16) short p_lds[4][64 * 72];   // 36.9 KB; oacc overlays after loop
    __shared__ float sm[4][64];
    __shared__ float sl[4][64];
    float* oacc = (float*)&p_lds[0][0];                 // 16 KB, lifetime-disjoint

    const int wg = blockIdx.x;            // 0..127 = bt*8 + h
    const int ck = blockIdx.y;            // chunk 0..3
    const int wgc = wg * 4 + ck;
    const int bt = wg >> 3, h = wg & 7;
    const int tid = threadIdx.x;
    const int wave = tid >> 6, lane = tid & 63;
    const int col = lane & 15, quad = lane >> 4;

    short8 qf[4][2];
    for (int mt = 0; mt < 4; mt++)
        for (int ks = 0; ks < 2; ks++)
            qf[mt][ks] = *(const short8*)(Q + (size_t)(bt * 64 + mt * 16 + col) * 512
                                            + h * 64 + ks * 32 + quad * 8);

    float m_run[4][4], l_run[4][4];
    f32x4 o_acc[4][4];
    for (int mt = 0; mt < 4; mt++)
        for (int r = 0; r < 4; r++) { m_run[mt][r] = -__builtin_inff(); l_run[mt][r] = 0.f; }
    for (int mt = 0; mt < 4; mt++)
        for (int dt = 0; dt < 4; dt++) o_acc[mt][dt] = f32x4{0.f, 0.f, 0.f, 0.f};

    short* pl = p_lds[wave];

    for (int jb = ck * 4 + wave; jb < 33; jb += 16) {
        f32x4 s[4][4];
        for (int mt = 0; mt < 4; mt++) for (int nt = 0; nt < 4; nt++) s[mt][nt] = f32x4{0.f, 0.f, 0.f, 0.f};
        for (int nt = 0; nt < 4; nt++) {
            const int j = jb * 64 + nt * 16 + col;
            const short* kp = Kb + (size_t)(bt * 2112 + j) * 512 + h * 64 + quad * 8;
            short8 k0 = *(const short8*)kp;
            short8 k1 = *(const short8*)(kp + 32);
            for (int mt = 0; mt < 4; mt++) {
                s[mt][nt] = __builtin_amdgcn_mfma_f32_16x16x32_bf16(qf[mt][0], k0, s[mt][nt], 0, 0, 0);
                s[mt][nt] = __builtin_amdgcn_mfma_f32_16x16x32_bf16(qf[mt][1], k1, s[mt][nt], 0, 0, 0);
            }
        }
        for (int mt = 0; mt < 4; mt++)
            for (int r = 0; r < 4; r++) {
                float mx = fmaxf(fmaxf(s[mt][0][r], s[mt][1][r]), fmaxf(s[mt][2][r], s[mt][3][r]));
                for (int off = 8; off >= 1; off >>= 1) mx = fmaxf(mx, __shfl_xor(mx, off));
                float mnew = fmaxf(m_run[mt][r], mx);
                float alpha = __expf(m_run[mt][r] - mnew);
                float rs = 0.f;
                for (int nt = 0; nt < 4; nt++) {
                    float p = __expf(s[mt][nt][r] - mnew);
                    s[mt][nt][r] = p;
                    rs += p;
                }
                for (int off = 8; off >= 1; off >>= 1) rs += __shfl_xor(rs, off);
                m_run[mt][r] = mnew;
                l_run[mt][r] = l_run[mt][r] * alpha + rs;
                for (int dt = 0; dt < 4; dt++) o_acc[mt][dt][r] *= alpha;
            }
        for (int mt = 0; mt < 4; mt++)
            for (int nt = 0; nt < 4; nt++)
                for (int r = 0; r < 4; r++)
                    pl[(mt * 16 + quad * 4 + r) * 72 + nt * 16 + col] = f2bf(s[mt][nt][r]);
        for (int ks = 0; ks < 2; ks++) {
            short8 vf[4];
            for (int dt = 0; dt < 4; dt++)
                vf[dt] = *(const short8*)(Vt + (size_t)(wg * 64 + dt * 16 + col) * 2112
                                             + jb * 64 + ks * 32 + quad * 8);
            for (int mt = 0; mt < 4; mt++) {
                short8 pf = *(const short8*)(pl + (mt * 16 + col) * 72 + ks * 32 + quad * 8);
                for (int dt = 0; dt < 4; dt++)
                    o_acc[mt][dt] = __builtin_amdgcn_mfma_f32_16x16x32_bf16(pf, vf[dt], o_acc[mt][dt], 0, 0, 0);
            }
        }
    }

    if (col == 0)
        for (int mt = 0; mt < 4; mt++)
            for (int r = 0; r < 4; r++) {
                int row = mt * 16 + quad * 4 + r;
                sm[wave][row] = m_run[mt][r];
                sl[wave][row] = l_run[mt][r];
            }
    __syncthreads();     // p_lds dead after this; oacc (same memory) goes live
    for (int mt = 0; mt < 4; mt++)
        for (int r = 0; r < 4; r++) {
            int row = mt * 16 + quad * 4 + r;
            float M = fmaxf(fmaxf(sm[0][row], sm[1][row]), fmaxf(sm[2][row], sm[3][row]));
            float L = sl[0][row] * __expf(sm[0][row] - M) + sl[1][row] * __expf(sm[1][row] - M)
                    + sl[2][row] * __expf(sm[2][row] - M) + sl[3][row] * __expf(sm[3][row] - M);
            if (wave == 0 && col == 0) { Mp[wgc * 64 + row] = M; Lp[wgc * 64 + row] = L; }
            float sc = __expf(m_run[mt][r] - M);
            for (int dt = 0; dt < 4; dt++) o_acc[mt][dt][r] *= sc;
        }
    for (int i = tid; i < 64 * 64; i += 256) oacc[i] = 0.f;
    __syncthreads();
    for (int w = 0; w < 4; w++) {
        if (wave == w)
            for (int mt = 0; mt < 4; mt++)
                for (int dt = 0; dt < 4; dt++)
                    for (int r = 0; r < 4; r++)
                        oacc[(mt * 16 + quad * 4 + r) * 64 + dt * 16 + col] += o_acc[mt][dt][r];
        __syncthreads();
    }
    for (int i = tid; i < 64 * 64; i += 256)
        Opart[(size_t)wgc * 4096 + i] = oacc[i];
}

// ---------- 5. merge chunk partials -> AttO (bf16) ----------
__global__ __launch_bounds__(256) void attn_merge(
    const float* __restrict__ Opart, const float* __restrict__ Mp,
    const float* __restrict__ Lp, short* __restrict__ AttO)
{
    int idx = blockIdx.x * 256 + threadIdx.x;  // 128*64*64
    int wg = idx >> 12, rd = idx & 4095, row = rd >> 6, d = rd & 63;
    float M = -__builtin_inff();
    for (int c = 0; c < 4; c++) M = fmaxf(M, Mp[(wg * 4 + c) * 64 + row]);
    float L = 0.f, O = 0.f;
    for (int c = 0; c < 4; c++) {
        float e = __expf(Mp[(wg * 4 + c) * 64 + row] - M);
        L += e * Lp[(wg * 4 + c) * 64 + row];
        O += e * Opart[(size_t)(wg * 4 + c) * 4096 + rd];
    }
    int bt = wg >> 3, h = wg & 7;
    AttO[(size_t)(bt * 64 + row) * 512 + h * 64 + d] = f2bf(O / L);
}

// ---------- launch ----------
extern "C" void kernel_launch(void* const* d_in, const int* in_sizes, int n_in,
                              void* d_out, int out_size, void* d_ws, size_t ws_size,
                              hipStream_t stream)
{
    const float* x   = (const float*)d_in[0];
    const float* lat = (const float*)d_in[1];
    const float* g_x = (const float*)d_in[2];
    const float* b_x = (const float*)d_in[3];
    const float* g_l = (const float*)d_in[4];
    const float* b_l = (const float*)d_in[5];
    const float* Wq  = (const float*)d_in[6];
    const float* Wkv = (const float*)d_in[7];
    const float* Wo  = (const float*)d_in[8];
    float* out = (float*)d_out;

    char* ws = (char*)d_ws;
    size_t off = 0;
    auto alloc = [&](size_t bytes) { char* p = ws + off; off += (bytes + 255) & ~(size_t)255; return p; };
    short* A_kvin = (short*)alloc(33792ull * 1024 * 2);  // 69.2 MB
    short* Lq     = (short*)alloc(1024ull * 1024 * 2);
    short* WkvT   = (short*)alloc(1024ull * 1024 * 2);
    short* WqT    = (short*)alloc(512ull * 1024 * 2);
    short* WoT    = (short*)alloc(1024ull * 512 * 2);
    short* Kb     = (short*)alloc(33792ull * 512 * 2);   // 34.6 MB
    short* Vt     = (short*)alloc(33792ull * 512 * 2);   // 34.6 MB (transposed V)
    short* Qb     = (short*)alloc(1024ull * 512 * 2);
    short* AttO   = (short*)alloc(1024ull * 512 * 2);
    float* Opart  = (float*)alloc(512ull * 4096 * 4);    // 8.4 MB
    float* Mp     = (float*)alloc(512ull * 64 * 4);
    float* Lp     = (float*)alloc(512ull * 64 * 4);

    prep_kernel<<<10496, 256, 0, stream>>>(x, lat, g_x, b_x, g_l, b_l, A_kvin, Lq,
                                           Wq, Wkv, Wo, WqT, WkvT, WoT);
    gemm_kvq<<<dim3(268, 8), 256, 0, stream>>>(A_kvin, WkvT, Kb, Vt, Lq, WqT, Qb);
    attn_kernel<<<dim3(128, 4), 256, 0, stream>>>(Qb, Kb, Vt, Opart, Mp, Lp);
    attn_merge<<<2048, 256, 0, stream>>>(Opart, Mp, Lp, AttO);
    gemm_out<<<dim3(8, 8), 256, 0, stream>>>(AttO, WoT, out);
}

// Round 6
// 379.794 us; speedup vs baseline: 1.2031x; 1.0139x over previous
//
#include <hip/hip_runtime.h>
#include <cstdint>
#include <cstddef>

// ---------- types ----------
typedef __attribute__((ext_vector_type(8))) short short8;   // 8 bf16 (4 VGPRs)
typedef __attribute__((ext_vector_type(4))) short short4v;  // 4 bf16
typedef __attribute__((ext_vector_type(4))) float f32x4;    // MFMA accum

__device__ __forceinline__ short f2bf(float f) {
    union { float f; unsigned u; } c; c.f = f;
    unsigned r = c.u + 0x7fffu + ((c.u >> 16) & 1u);   // RNE
    return (short)(r >> 16);
}

// async global->LDS, 16B per lane; LDS dest must be wave-uniform base + lane*16
__device__ __forceinline__ void gl2lds16(const void* g, void* l) {
    __builtin_amdgcn_global_load_lds(
        (const __attribute__((address_space(1))) void*)g,
        (__attribute__((address_space(3))) void*)l, 16, 0, 0);
}

// ---------- 1. prep: LayerNorm (blocks 0..8447) + weight transposes (8448..10495) ----------
__global__ __launch_bounds__(256) void prep_kernel(
    const float* __restrict__ x, const float* __restrict__ lat,
    const float* __restrict__ gx, const float* __restrict__ bx,
    const float* __restrict__ gl, const float* __restrict__ bl,
    short* __restrict__ Aout, short* __restrict__ Lq,
    const float* __restrict__ Wq, const float* __restrict__ Wkv, const float* __restrict__ Wo,
    short* __restrict__ WqT, short* __restrict__ WkvT, short* __restrict__ WoT)
{
    __shared__ float t[32][33];
    if (blockIdx.x < 8448) {
        // ---- LayerNorm, one wave per row ----
        const int wave = threadIdx.x >> 6, lane = threadIdx.x & 63;
        const int r = blockIdx.x * 4 + wave;   // 0..33791
        const float *src, *g, *b; size_t drow; short* dst2 = nullptr;
        if (r < 32768) {
            int bt = r >> 11, i = r & 2047;
            src = x + (size_t)r * 1024; g = gx; b = bx;
            drow = (size_t)bt * 2112 + i;
        } else {
            int idx = r - 32768;
            int bt = idx >> 6, i = idx & 63;
            src = lat + (size_t)idx * 1024; g = gl; b = bl;
            drow = (size_t)bt * 2112 + 2048 + i;
            dst2 = Lq + (size_t)idx * 1024;
        }
        float4 v[4];
        for (int j = 0; j < 4; j++) v[j] = ((const float4*)src)[lane + 64 * j];
        float s = 0.f, s2 = 0.f;
        for (int j = 0; j < 4; j++) {
            s  += v[j].x + v[j].y + v[j].z + v[j].w;
            s2 += v[j].x * v[j].x + v[j].y * v[j].y + v[j].z * v[j].z + v[j].w * v[j].w;
        }
        for (int off = 32; off >= 1; off >>= 1) { s += __shfl_xor(s, off); s2 += __shfl_xor(s2, off); }
        const float mu   = s * (1.f / 1024.f);
        const float rstd = rsqrtf(s2 * (1.f / 1024.f) - mu * mu + 1e-5f);
        for (int j = 0; j < 4; j++) {
            float4 gv = ((const float4*)g)[lane + 64 * j];
            float4 bv = ((const float4*)b)[lane + 64 * j];
            short4v o;
            o[0] = f2bf((v[j].x - mu) * rstd * gv.x + bv.x);
            o[1] = f2bf((v[j].y - mu) * rstd * gv.y + bv.y);
            o[2] = f2bf((v[j].z - mu) * rstd * gv.z + bv.z);
            o[3] = f2bf((v[j].w - mu) * rstd * gv.w + bv.w);
            *(short4v*)(Aout + drow * 1024 + (size_t)(lane + 64 * j) * 4) = o;
            if (dst2) *(short4v*)(dst2 + (size_t)(lane + 64 * j) * 4) = o;
        }
    } else {
        // ---- weight transpose via LDS tile ----
        const int id = blockIdx.x - 8448;
        const float* S; short* D; int K, N, kt, nt; float scale = 1.0f;
        if (id < 1024)      { S = Wkv; D = WkvT; K = 1024; N = 1024; kt = (id >> 5) * 32;          nt = (id & 31) * 32; }
        else if (id < 1536) { S = Wq;  D = WqT;  K = 1024; N = 512;  kt = ((id - 1024) >> 4) * 32; nt = ((id - 1024) & 15) * 32; scale = 0.125f; }
        else                { S = Wo;  D = WoT;  K = 512;  N = 1024; kt = ((id - 1536) >> 5) * 32; nt = ((id - 1536) & 31) * 32; }
        const int xx = threadIdx.x & 31, y4 = (threadIdx.x >> 5) * 4;
        for (int i = 0; i < 4; i++)
            t[y4 + i][xx] = S[(size_t)(kt + y4 + i) * N + nt + xx];
        __syncthreads();
        for (int i = 0; i < 4; i++)
            D[(size_t)(nt + y4 + i) * K + kt + xx] = f2bf(t[xx][y4 + i] * scale);
    }
}

// ---------- 2. fused kv+q GEMM, K=1024, BK=32 (round-4 proven), 16 KB LDS ----------
// grid (268, 8), x = m-tile FASTEST (linear%8 -> XCD spreads m; B panel L2-resident).
// x<264: kv tile. Epilogue: n<512 -> Kb (512-wide); n>=512 -> Vt transposed.
// x>=264: q tile, extra=(x-264)*8+y in [0,32): qm=extra>>2, qn=extra&3 -> Qb.
// __launch_bounds__(256,3): request 3 blocks/CU residency (68+64 unified regs fits).
__global__ __launch_bounds__(256, 3) void gemm_kvq(
    const short* __restrict__ A, const short* __restrict__ Bt,
    short* __restrict__ Kb, short* __restrict__ Vt,
    const short* __restrict__ Aq, const short* __restrict__ Btq, short* __restrict__ Qb)
{
    __shared__ short As[128 * 32];
    __shared__ short Bs[128 * 32];
    const int tid  = threadIdx.x;
    const int wave = tid >> 6, lane = tid & 63;
    const int col  = lane & 15, quad = lane >> 4;
    const short *pA, *pB; int m0, n0, kvmode;
    if (blockIdx.x < 264) {
        pA = A; pB = Bt; kvmode = 1;
        m0 = blockIdx.x * 128; n0 = blockIdx.y * 128;
    } else {
        int extra = (blockIdx.x - 264) * 8 + blockIdx.y;
        pA = Aq; pB = Btq; kvmode = 0;
        m0 = (extra >> 2) * 128; n0 = (extra & 3) * 128;
    }
    const int K = 1024;
    const int wm = (wave >> 1) * 64, wn = (wave & 1) * 64;
    const int sr = tid >> 2;           // staging row 0..63
    const int sk = (tid & 3) * 8;      // staging k offset (shorts)

    f32x4 acc[4][4];
    for (int i = 0; i < 4; i++) for (int j = 0; j < 4; j++) acc[i][j] = f32x4{0.f, 0.f, 0.f, 0.f};

    const short* Ar0 = pA + (size_t)(m0 + sr)      * K + sk;
    const short* Ar1 = pA + (size_t)(m0 + sr + 64) * K + sk;
    const short* Br0 = pB + (size_t)(n0 + sr)      * K + sk;
    const short* Br1 = pB + (size_t)(n0 + sr + 64) * K + sk;
    short* lA0 = &As[sr * 32 + sk];
    short* lA1 = &As[(sr + 64) * 32 + sk];
    short* lB0 = &Bs[sr * 32 + sk];
    short* lB1 = &Bs[(sr + 64) * 32 + sk];

    for (int k0 = 0; k0 < K; k0 += 32) {
        __syncthreads();
        gl2lds16(Ar0 + k0, lA0);
        gl2lds16(Ar1 + k0, lA1);
        gl2lds16(Br0 + k0, lB0);
        gl2lds16(Br1 + k0, lB1);
        __syncthreads();
        short8 af[4], bf[4];
        for (int mt = 0; mt < 4; mt++) af[mt] = *(const short8*)&As[(wm + mt * 16 + col) * 32 + quad * 8];
        for (int nt = 0; nt < 4; nt++) bf[nt] = *(const short8*)&Bs[(wn + nt * 16 + col) * 32 + quad * 8];
        for (int mt = 0; mt < 4; mt++)
            for (int nt = 0; nt < 4; nt++)
                acc[mt][nt] = __builtin_amdgcn_mfma_f32_16x16x32_bf16(af[mt], bf[nt], acc[mt][nt], 0, 0, 0);
    }
    if (kvmode) {
        for (int mt = 0; mt < 4; mt++)
            for (int nt = 0; nt < 4; nt++) {
                int ng = n0 + wn + nt * 16 + col;
                int base_m = m0 + wm + mt * 16 + quad * 4;
                if (ng < 512) {
                    for (int r = 0; r < 4; r++)
                        Kb[(size_t)(base_m + r) * 512 + ng] = f2bf(acc[mt][nt][r]);
                } else {
                    int nv = ng - 512, h = nv >> 6, d = nv & 63;
                    int bt = base_m / 2112, j = base_m - bt * 2112;  // 4-row group never straddles bt
                    short4v pk;
                    for (int r = 0; r < 4; r++) pk[r] = f2bf(acc[mt][nt][r]);
                    *(short4v*)&Vt[(size_t)((bt * 8 + h) * 64 + d) * 2112 + j] = pk;
                }
            }
    } else {
        for (int mt = 0; mt < 4; mt++)
            for (int nt = 0; nt < 4; nt++)
                for (int r = 0; r < 4; r++) {
                    int row = m0 + wm + mt * 16 + quad * 4 + r;
                    int cc  = n0 + wn + nt * 16 + col;
                    Qb[(size_t)row * 512 + cc] = f2bf(acc[mt][nt][r]);
                }
    }
}

// ---------- 3. out-projection GEMM, K=512, BK=64 x2 sub-tiles (64 blocks: 1/CU,
//             occupancy can't bite -> fewer barriers is a pure win), fp32 out ----------
__global__ __launch_bounds__(256) void gemm_out(
    const short* __restrict__ A, const short* __restrict__ Bt, float* __restrict__ C)
{
    __shared__ short As0[128 * 32], As1[128 * 32];
    __shared__ short Bs0[128 * 32], Bs1[128 * 32];
    const int tid  = threadIdx.x;
    const int wave = tid >> 6, lane = tid & 63;
    const int col  = lane & 15, quad = lane >> 4;
    const int m0 = blockIdx.x * 128, n0 = blockIdx.y * 128;
    const int K = 512, N = 1024;
    const int wm = (wave >> 1) * 64, wn = (wave & 1) * 64;
    const int sr = tid >> 2, sk = (tid & 3) * 8;

    f32x4 acc[4][4];
    for (int i = 0; i < 4; i++) for (int j = 0; j < 4; j++) acc[i][j] = f32x4{0.f, 0.f, 0.f, 0.f};

    const short* Ar0 = A  + (size_t)(m0 + sr)      * K + sk;
    const short* Ar1 = A  + (size_t)(m0 + sr + 64) * K + sk;
    const short* Br0 = Bt + (size_t)(n0 + sr)      * K + sk;
    const short* Br1 = Bt + (size_t)(n0 + sr + 64) * K + sk;
    short* lA0 = &As0[sr * 32 + sk];  short* lA1 = &As0[(sr + 64) * 32 + sk];
    short* lA2 = &As1[sr * 32 + sk];  short* lA3 = &As1[(sr + 64) * 32 + sk];
    short* lB0 = &Bs0[sr * 32 + sk];  short* lB1 = &Bs0[(sr + 64) * 32 + sk];
    short* lB2 = &Bs1[sr * 32 + sk];  short* lB3 = &Bs1[(sr + 64) * 32 + sk];

    for (int k0 = 0; k0 < K; k0 += 64) {
        __syncthreads();
        gl2lds16(Ar0 + k0, lA0);      gl2lds16(Ar1 + k0, lA1);
        gl2lds16(Ar0 + k0 + 32, lA2); gl2lds16(Ar1 + k0 + 32, lA3);
        gl2lds16(Br0 + k0, lB0);      gl2lds16(Br1 + k0, lB1);
        gl2lds16(Br0 + k0 + 32, lB2); gl2lds16(Br1 + k0 + 32, lB3);
        __syncthreads();
        {
            short8 af[4], bf[4];
            for (int mt = 0; mt < 4; mt++) af[mt] = *(const short8*)&As0[(wm + mt * 16 + col) * 32 + quad * 8];
            for (int nt = 0; nt < 4; nt++) bf[nt] = *(const short8*)&Bs0[(wn + nt * 16 + col) * 32 + quad * 8];
            for (int mt = 0; mt < 4; mt++)
                for (int nt = 0; nt < 4; nt++)
                    acc[mt][nt] = __builtin_amdgcn_mfma_f32_16x16x32_bf16(af[mt], bf[nt], acc[mt][nt], 0, 0, 0);
        }
        {
            short8 af[4], bf[4];
            for (int mt = 0; mt < 4; mt++) af[mt] = *(const short8*)&As1[(wm + mt * 16 + col) * 32 + quad * 8];
            for (int nt = 0; nt < 4; nt++) bf[nt] = *(const short8*)&Bs1[(wn + nt * 16 + col) * 32 + quad * 8];
            for (int mt = 0; mt < 4; mt++)
                for (int nt = 0; nt < 4; nt++)
                    acc[mt][nt] = __builtin_amdgcn_mfma_f32_16x16x32_bf16(af[mt], bf[nt], acc[mt][nt], 0, 0, 0);
        }
    }
    for (int mt = 0; mt < 4; mt++)
        for (int nt = 0; nt < 4; nt++)
            for (int r = 0; r < 4; r++) {
                int row = m0 + wm + mt * 16 + quad * 4 + r;
                int cc  = n0 + wn + nt * 16 + col;
                C[(size_t)row * N + cc] = acc[mt][nt][r];
            }
}

// ---------- 4. attention: grid (128 wg, 4 chunks); un-normalized partials ----------
__global__ __launch_bounds__(256) void attn_kernel(
    const short* __restrict__ Q,    // (1024, 512)
    const short* __restrict__ Kb,   // (33792, 512)
    const short* __restrict__ Vt,   // (128*64, 2112)
    float* __restrict__ Opart,      // (512, 64, 64)
    float* __restrict__ Mp,         // (512, 64)
    float* __restrict__ Lp)         // (512, 64)
{
    __shared__ __align__(16) short p_lds[4][64 * 72];   // 36.9 KB; oacc overlays after loop
    __shared__ float sm[4][64];
    __shared__ float sl[4][64];
    float* oacc = (float*)&p_lds[0][0];                 // 16 KB, lifetime-disjoint

    const int wg = blockIdx.x;            // 0..127 = bt*8 + h
    const int ck = blockIdx.y;            // chunk 0..3
    const int wgc = wg * 4 + ck;
    const int bt = wg >> 3, h = wg & 7;
    const int tid = threadIdx.x;
    const int wave = tid >> 6, lane = tid & 63;
    const int col = lane & 15, quad = lane >> 4;

    short8 qf[4][2];
    for (int mt = 0; mt < 4; mt++)
        for (int ks = 0; ks < 2; ks++)
            qf[mt][ks] = *(const short8*)(Q + (size_t)(bt * 64 + mt * 16 + col) * 512
                                            + h * 64 + ks * 32 + quad * 8);

    float m_run[4][4], l_run[4][4];
    f32x4 o_acc[4][4];
    for (int mt = 0; mt < 4; mt++)
        for (int r = 0; r < 4; r++) { m_run[mt][r] = -__builtin_inff(); l_run[mt][r] = 0.f; }
    for (int mt = 0; mt < 4; mt++)
        for (int dt = 0; dt < 4; dt++) o_acc[mt][dt] = f32x4{0.f, 0.f, 0.f, 0.f};

    short* pl = p_lds[wave];

    for (int jb = ck * 4 + wave; jb < 33; jb += 16) {
        f32x4 s[4][4];
        for (int mt = 0; mt < 4; mt++) for (int nt = 0; nt < 4; nt++) s[mt][nt] = f32x4{0.f, 0.f, 0.f, 0.f};
        for (int nt = 0; nt < 4; nt++) {
            const int j = jb * 64 + nt * 16 + col;
            const short* kp = Kb + (size_t)(bt * 2112 + j) * 512 + h * 64 + quad * 8;
            short8 k0 = *(const short8*)kp;
            short8 k1 = *(const short8*)(kp + 32);
            for (int mt = 0; mt < 4; mt++) {
                s[mt][nt] = __builtin_amdgcn_mfma_f32_16x16x32_bf16(qf[mt][0], k0, s[mt][nt], 0, 0, 0);
                s[mt][nt] = __builtin_amdgcn_mfma_f32_16x16x32_bf16(qf[mt][1], k1, s[mt][nt], 0, 0, 0);
            }
        }
        for (int mt = 0; mt < 4; mt++)
            for (int r = 0; r < 4; r++) {
                float mx = fmaxf(fmaxf(s[mt][0][r], s[mt][1][r]), fmaxf(s[mt][2][r], s[mt][3][r]));
                for (int off = 8; off >= 1; off >>= 1) mx = fmaxf(mx, __shfl_xor(mx, off));
                float mnew = fmaxf(m_run[mt][r], mx);
                float alpha = __expf(m_run[mt][r] - mnew);
                float rs = 0.f;
                for (int nt = 0; nt < 4; nt++) {
                    float p = __expf(s[mt][nt][r] - mnew);
                    s[mt][nt][r] = p;
                    rs += p;
                }
                for (int off = 8; off >= 1; off >>= 1) rs += __shfl_xor(rs, off);
                m_run[mt][r] = mnew;
                l_run[mt][r] = l_run[mt][r] * alpha + rs;
                for (int dt = 0; dt < 4; dt++) o_acc[mt][dt][r] *= alpha;
            }
        for (int mt = 0; mt < 4; mt++)
            for (int nt = 0; nt < 4; nt++)
                for (int r = 0; r < 4; r++)
                    pl[(mt * 16 + quad * 4 + r) * 72 + nt * 16 + col] = f2bf(s[mt][nt][r]);
        for (int ks = 0; ks < 2; ks++) {
            short8 vf[4];
            for (int dt = 0; dt < 4; dt++)
                vf[dt] = *(const short8*)(Vt + (size_t)(wg * 64 + dt * 16 + col) * 2112
                                             + jb * 64 + ks * 32 + quad * 8);
            for (int mt = 0; mt < 4; mt++) {
                short8 pf = *(const short8*)(pl + (mt * 16 + col) * 72 + ks * 32 + quad * 8);
                for (int dt = 0; dt < 4; dt++)
                    o_acc[mt][dt] = __builtin_amdgcn_mfma_f32_16x16x32_bf16(pf, vf[dt], o_acc[mt][dt], 0, 0, 0);
            }
        }
    }

    if (col == 0)
        for (int mt = 0; mt < 4; mt++)
            for (int r = 0; r < 4; r++) {
                int row = mt * 16 + quad * 4 + r;
                sm[wave][row] = m_run[mt][r];
                sl[wave][row] = l_run[mt][r];
            }
    __syncthreads();     // p_lds dead after this; oacc (same memory) goes live
    for (int mt = 0; mt < 4; mt++)
        for (int r = 0; r < 4; r++) {
            int row = mt * 16 + quad * 4 + r;
            float M = fmaxf(fmaxf(sm[0][row], sm[1][row]), fmaxf(sm[2][row], sm[3][row]));
            float L = sl[0][row] * __expf(sm[0][row] - M) + sl[1][row] * __expf(sm[1][row] - M)
                    + sl[2][row] * __expf(sm[2][row] - M) + sl[3][row] * __expf(sm[3][row] - M);
            if (wave == 0 && col == 0) { Mp[wgc * 64 + row] = M; Lp[wgc * 64 + row] = L; }
            float sc = __expf(m_run[mt][r] - M);
            for (int dt = 0; dt < 4; dt++) o_acc[mt][dt][r] *= sc;
        }
    for (int i = tid; i < 64 * 64; i += 256) oacc[i] = 0.f;
    __syncthreads();
    for (int w = 0; w < 4; w++) {
        if (wave == w)
            for (int mt = 0; mt < 4; mt++)
                for (int dt = 0; dt < 4; dt++)
                    for (int r = 0; r < 4; r++)
                        oacc[(mt * 16 + quad * 4 + r) * 64 + dt * 16 + col] += o_acc[mt][dt][r];
        __syncthreads();
    }
    for (int i = tid; i < 64 * 64; i += 256)
        Opart[(size_t)wgc * 4096 + i] = oacc[i];
}

// ---------- 5. merge chunk partials -> AttO (bf16) ----------
__global__ __launch_bounds__(256) void attn_merge(
    const float* __restrict__ Opart, const float* __restrict__ Mp,
    const float* __restrict__ Lp, short* __restrict__ AttO)
{
    int idx = blockIdx.x * 256 + threadIdx.x;  // 128*64*64
    int wg = idx >> 12, rd = idx & 4095, row = rd >> 6, d = rd & 63;
    float M = -__builtin_inff();
    for (int c = 0; c < 4; c++) M = fmaxf(M, Mp[(wg * 4 + c) * 64 + row]);
    float L = 0.f, O = 0.f;
    for (int c = 0; c < 4; c++) {
        float e = __expf(Mp[(wg * 4 + c) * 64 + row] - M);
        L += e * Lp[(wg * 4 + c) * 64 + row];
        O += e * Opart[(size_t)(wg * 4 + c) * 4096 + rd];
    }
    int bt = wg >> 3, h = wg & 7;
    AttO[(size_t)(bt * 64 + row) * 512 + h * 64 + d] = f2bf(O / L);
}

// ---------- launch ----------
extern "C" void kernel_launch(void* const* d_in, const int* in_sizes, int n_in,
                              void* d_out, int out_size, void* d_ws, size_t ws_size,
                              hipStream_t stream)
{
    const float* x   = (const float*)d_in[0];
    const float* lat = (const float*)d_in[1];
    const float* g_x = (const float*)d_in[2];
    const float* b_x = (const float*)d_in[3];
    const float* g_l = (const float*)d_in[4];
    const float* b_l = (const float*)d_in[5];
    const float* Wq  = (const float*)d_in[6];
    const float* Wkv = (const float*)d_in[7];
    const float* Wo  = (const float*)d_in[8];
    float* out = (float*)d_out;

    char* ws = (char*)d_ws;
    size_t off = 0;
    auto alloc = [&](size_t bytes) { char* p = ws + off; off += (bytes + 255) & ~(size_t)255; return p; };
    short* A_kvin = (short*)alloc(33792ull * 1024 * 2);  // 69.2 MB
    short* Lq     = (short*)alloc(1024ull * 1024 * 2);
    short* WkvT   = (short*)alloc(1024ull * 1024 * 2);
    short* WqT    = (short*)alloc(512ull * 1024 * 2);
    short* WoT    = (short*)alloc(1024ull * 512 * 2);
    short* Kb     = (short*)alloc(33792ull * 512 * 2);   // 34.6 MB
    short* Vt     = (short*)alloc(33792ull * 512 * 2);   // 34.6 MB (transposed V)
    short* Qb     = (short*)alloc(1024ull * 512 * 2);
    short* AttO   = (short*)alloc(1024ull * 512 * 2);
    float* Opart  = (float*)alloc(512ull * 4096 * 4);    // 8.4 MB
    float* Mp     = (float*)alloc(512ull * 64 * 4);
    float* Lp     = (float*)alloc(512ull * 64 * 4);

    prep_kernel<<<10496, 256, 0, stream>>>(x, lat, g_x, b_x, g_l, b_l, A_kvin, Lq,
                                           Wq, Wkv, Wo, WqT, WkvT, WoT);
    gemm_kvq<<<dim3(268, 8), 256, 0, stream>>>(A_kvin, WkvT, Kb, Vt, Lq, WqT, Qb);
    attn_kernel<<<dim3(128, 4), 256, 0, stream>>>(Qb, Kb, Vt, Opart, Mp, Lp);
    attn_merge<<<2048, 256, 0, stream>>>(Opart, Mp, Lp, AttO);
    gemm_out<<<dim3(8, 8), 256, 0, stream>>>(AttO, WoT, out);
}

// Round 7
// 366.795 us; speedup vs baseline: 1.2457x; 1.0354x over previous
//
#include <hip/hip_runtime.h>
#include <cstdint>
#include <cstddef>

// ---------- types ----------
typedef __attribute__((ext_vector_type(8))) short short8;   // 8 bf16 (4 VGPRs)
typedef __attribute__((ext_vector_type(4))) short short4v;  // 4 bf16
typedef __attribute__((ext_vector_type(4))) float f32x4;    // MFMA accum

__device__ __forceinline__ short f2bf(float f) {
    union { float f; unsigned u; } c; c.f = f;
    unsigned r = c.u + 0x7fffu + ((c.u >> 16) & 1u);   // RNE
    return (short)(r >> 16);
}

// async global->LDS, 16B per lane; LDS dest must be wave-uniform base + lane*16
__device__ __forceinline__ void gl2lds16(const void* g, void* l) {
    __builtin_amdgcn_global_load_lds(
        (const __attribute__((address_space(1))) void*)g,
        (__attribute__((address_space(3))) void*)l, 16, 0, 0);
}

// ---------- 1. prep: LayerNorm (blocks 0..8447) + weight transposes (8448..10495) ----------
__global__ __launch_bounds__(256) void prep_kernel(
    const float* __restrict__ x, const float* __restrict__ lat,
    const float* __restrict__ gx, const float* __restrict__ bx,
    const float* __restrict__ gl, const float* __restrict__ bl,
    short* __restrict__ Aout, short* __restrict__ Lq,
    const float* __restrict__ Wq, const float* __restrict__ Wkv, const float* __restrict__ Wo,
    short* __restrict__ WqT, short* __restrict__ WkvT, short* __restrict__ WoT)
{
    __shared__ float t[32][33];
    if (blockIdx.x < 8448) {
        // ---- LayerNorm, one wave per row ----
        const int wave = threadIdx.x >> 6, lane = threadIdx.x & 63;
        const int r = blockIdx.x * 4 + wave;   // 0..33791
        const float *src, *g, *b; size_t drow; short* dst2 = nullptr;
        if (r < 32768) {
            int bt = r >> 11, i = r & 2047;
            src = x + (size_t)r * 1024; g = gx; b = bx;
            drow = (size_t)bt * 2112 + i;
        } else {
            int idx = r - 32768;
            int bt = idx >> 6, i = idx & 63;
            src = lat + (size_t)idx * 1024; g = gl; b = bl;
            drow = (size_t)bt * 2112 + 2048 + i;
            dst2 = Lq + (size_t)idx * 1024;
        }
        float4 v[4];
        for (int j = 0; j < 4; j++) v[j] = ((const float4*)src)[lane + 64 * j];
        float s = 0.f, s2 = 0.f;
        for (int j = 0; j < 4; j++) {
            s  += v[j].x + v[j].y + v[j].z + v[j].w;
            s2 += v[j].x * v[j].x + v[j].y * v[j].y + v[j].z * v[j].z + v[j].w * v[j].w;
        }
        for (int off = 32; off >= 1; off >>= 1) { s += __shfl_xor(s, off); s2 += __shfl_xor(s2, off); }
        const float mu   = s * (1.f / 1024.f);
        const float rstd = rsqrtf(s2 * (1.f / 1024.f) - mu * mu + 1e-5f);
        for (int j = 0; j < 4; j++) {
            float4 gv = ((const float4*)g)[lane + 64 * j];
            float4 bv = ((const float4*)b)[lane + 64 * j];
            short4v o;
            o[0] = f2bf((v[j].x - mu) * rstd * gv.x + bv.x);
            o[1] = f2bf((v[j].y - mu) * rstd * gv.y + bv.y);
            o[2] = f2bf((v[j].z - mu) * rstd * gv.z + bv.z);
            o[3] = f2bf((v[j].w - mu) * rstd * gv.w + bv.w);
            *(short4v*)(Aout + drow * 1024 + (size_t)(lane + 64 * j) * 4) = o;
            if (dst2) *(short4v*)(dst2 + (size_t)(lane + 64 * j) * 4) = o;
        }
    } else {
        // ---- weight transpose via LDS tile ----
        const int id = blockIdx.x - 8448;
        const float* S; short* D; int K, N, kt, nt; float scale = 1.0f;
        if (id < 1024)      { S = Wkv; D = WkvT; K = 1024; N = 1024; kt = (id >> 5) * 32;          nt = (id & 31) * 32; }
        else if (id < 1536) { S = Wq;  D = WqT;  K = 1024; N = 512;  kt = ((id - 1024) >> 4) * 32; nt = ((id - 1024) & 15) * 32; scale = 0.125f; }
        else                { S = Wo;  D = WoT;  K = 512;  N = 1024; kt = ((id - 1536) >> 5) * 32; nt = ((id - 1536) & 31) * 32; }
        const int xx = threadIdx.x & 31, y4 = (threadIdx.x >> 5) * 4;
        for (int i = 0; i < 4; i++)
            t[y4 + i][xx] = S[(size_t)(kt + y4 + i) * N + nt + xx];
        __syncthreads();
        for (int i = 0; i < 4; i++)
            D[(size_t)(nt + y4 + i) * K + kt + xx] = f2bf(t[xx][y4 + i] * scale);
    }
}

// ---------- 2. fused kv+q GEMM, K=1024, BK=32, 16 KB LDS, SUPERTILE swizzle -------
// 1D grid, 2144 blocks. Blocks [0,2112) = kv tiles remapped in generations of 768
// (=256 CU x 3 blocks/CU): within a generation x (m-tile) varies fastest over 96
// (last gen: 72), y over all 8 n-tiles. Blocks sharing an A m-tile are 96 apart
// -> same linear%8 -> same XCD (96%8==768%8==0): A-tile fetched into that XCD's
// L2 once, reused by all 8 n-tiles. Per-XCD working set ~3MB A + 2MB B ~= L2.
// Blocks [2112,2144) = q tiles (8 m x 4 n).
__global__ __launch_bounds__(256, 3) void gemm_kvq(
    const short* __restrict__ A, const short* __restrict__ Bt,
    short* __restrict__ Kb, short* __restrict__ Vt,
    const short* __restrict__ Aq, const short* __restrict__ Btq, short* __restrict__ Qb)
{
    __shared__ short As[128 * 32];
    __shared__ short Bs[128 * 32];
    const int tid  = threadIdx.x;
    const int wave = tid >> 6, lane = tid & 63;
    const int col  = lane & 15, quad = lane >> 4;
    const int lin = blockIdx.x;
    const short *pA, *pB; int m0, n0, kvmode;
    if (lin < 2112) {
        pA = A; pB = Bt; kvmode = 1;
        int xt, yt;
        if (lin < 1536) { int g = lin / 768, r = lin % 768; xt = g * 96 + r % 96; yt = r / 96; }
        else            { int r = lin - 1536;               xt = 192 + r % 72;    yt = r / 72; }
        m0 = xt * 128; n0 = yt * 128;
    } else {
        int extra = lin - 2112;
        pA = Aq; pB = Btq; kvmode = 0;
        m0 = (extra >> 2) * 128; n0 = (extra & 3) * 128;
    }
    const int K = 1024;
    const int wm = (wave >> 1) * 64, wn = (wave & 1) * 64;
    const int sr = tid >> 2;           // staging row 0..63
    const int sk = (tid & 3) * 8;      // staging k offset (shorts)

    f32x4 acc[4][4];
    for (int i = 0; i < 4; i++) for (int j = 0; j < 4; j++) acc[i][j] = f32x4{0.f, 0.f, 0.f, 0.f};

    const short* Ar0 = pA + (size_t)(m0 + sr)      * K + sk;
    const short* Ar1 = pA + (size_t)(m0 + sr + 64) * K + sk;
    const short* Br0 = pB + (size_t)(n0 + sr)      * K + sk;
    const short* Br1 = pB + (size_t)(n0 + sr + 64) * K + sk;
    short* lA0 = &As[sr * 32 + sk];
    short* lA1 = &As[(sr + 64) * 32 + sk];
    short* lB0 = &Bs[sr * 32 + sk];
    short* lB1 = &Bs[(sr + 64) * 32 + sk];

    for (int k0 = 0; k0 < K; k0 += 32) {
        __syncthreads();
        gl2lds16(Ar0 + k0, lA0);
        gl2lds16(Ar1 + k0, lA1);
        gl2lds16(Br0 + k0, lB0);
        gl2lds16(Br1 + k0, lB1);
        __syncthreads();
        short8 af[4], bf[4];
        for (int mt = 0; mt < 4; mt++) af[mt] = *(const short8*)&As[(wm + mt * 16 + col) * 32 + quad * 8];
        for (int nt = 0; nt < 4; nt++) bf[nt] = *(const short8*)&Bs[(wn + nt * 16 + col) * 32 + quad * 8];
        for (int mt = 0; mt < 4; mt++)
            for (int nt = 0; nt < 4; nt++)
                acc[mt][nt] = __builtin_amdgcn_mfma_f32_16x16x32_bf16(af[mt], bf[nt], acc[mt][nt], 0, 0, 0);
    }
    if (kvmode) {
        for (int mt = 0; mt < 4; mt++)
            for (int nt = 0; nt < 4; nt++) {
                int ng = n0 + wn + nt * 16 + col;
                int base_m = m0 + wm + mt * 16 + quad * 4;
                if (ng < 512) {
                    for (int r = 0; r < 4; r++)
                        Kb[(size_t)(base_m + r) * 512 + ng] = f2bf(acc[mt][nt][r]);
                } else {
                    int nv = ng - 512, h = nv >> 6, d = nv & 63;
                    int bt = base_m / 2112, j = base_m - bt * 2112;  // 4-row group never straddles bt
                    short4v pk;
                    for (int r = 0; r < 4; r++) pk[r] = f2bf(acc[mt][nt][r]);
                    *(short4v*)&Vt[(size_t)((bt * 8 + h) * 64 + d) * 2112 + j] = pk;
                }
            }
    } else {
        for (int mt = 0; mt < 4; mt++)
            for (int nt = 0; nt < 4; nt++)
                for (int r = 0; r < 4; r++) {
                    int row = m0 + wm + mt * 16 + quad * 4 + r;
                    int cc  = n0 + wn + nt * 16 + col;
                    Qb[(size_t)row * 512 + cc] = f2bf(acc[mt][nt][r]);
                }
    }
}

// ---------- 3. out-projection GEMM, K=512, BK=64 x2 sub-tiles (64 blocks: 1/CU), fp32 out ----------
__global__ __launch_bounds__(256) void gemm_out(
    const short* __restrict__ A, const short* __restrict__ Bt, float* __restrict__ C)
{
    __shared__ short As0[128 * 32], As1[128 * 32];
    __shared__ short Bs0[128 * 32], Bs1[128 * 32];
    const int tid  = threadIdx.x;
    const int wave = tid >> 6, lane = tid & 63;
    const int col  = lane & 15, quad = lane >> 4;
    const int m0 = blockIdx.x * 128, n0 = blockIdx.y * 128;
    const int K = 512, N = 1024;
    const int wm = (wave >> 1) * 64, wn = (wave & 1) * 64;
    const int sr = tid >> 2, sk = (tid & 3) * 8;

    f32x4 acc[4][4];
    for (int i = 0; i < 4; i++) for (int j = 0; j < 4; j++) acc[i][j] = f32x4{0.f, 0.f, 0.f, 0.f};

    const short* Ar0 = A  + (size_t)(m0 + sr)      * K + sk;
    const short* Ar1 = A  + (size_t)(m0 + sr + 64) * K + sk;
    const short* Br0 = Bt + (size_t)(n0 + sr)      * K + sk;
    const short* Br1 = Bt + (size_t)(n0 + sr + 64) * K + sk;
    short* lA0 = &As0[sr * 32 + sk];  short* lA1 = &As0[(sr + 64) * 32 + sk];
    short* lA2 = &As1[sr * 32 + sk];  short* lA3 = &As1[(sr + 64) * 32 + sk];
    short* lB0 = &Bs0[sr * 32 + sk];  short* lB1 = &Bs0[(sr + 64) * 32 + sk];
    short* lB2 = &Bs1[sr * 32 + sk];  short* lB3 = &Bs1[(sr + 64) * 32 + sk];

    for (int k0 = 0; k0 < K; k0 += 64) {
        __syncthreads();
        gl2lds16(Ar0 + k0, lA0);      gl2lds16(Ar1 + k0, lA1);
        gl2lds16(Ar0 + k0 + 32, lA2); gl2lds16(Ar1 + k0 + 32, lA3);
        gl2lds16(Br0 + k0, lB0);      gl2lds16(Br1 + k0, lB1);
        gl2lds16(Br0 + k0 + 32, lB2); gl2lds16(Br1 + k0 + 32, lB3);
        __syncthreads();
        {
            short8 af[4], bf[4];
            for (int mt = 0; mt < 4; mt++) af[mt] = *(const short8*)&As0[(wm + mt * 16 + col) * 32 + quad * 8];
            for (int nt = 0; nt < 4; nt++) bf[nt] = *(const short8*)&Bs0[(wn + nt * 16 + col) * 32 + quad * 8];
            for (int mt = 0; mt < 4; mt++)
                for (int nt = 0; nt < 4; nt++)
                    acc[mt][nt] = __builtin_amdgcn_mfma_f32_16x16x32_bf16(af[mt], bf[nt], acc[mt][nt], 0, 0, 0);
        }
        {
            short8 af[4], bf[4];
            for (int mt = 0; mt < 4; mt++) af[mt] = *(const short8*)&As1[(wm + mt * 16 + col) * 32 + quad * 8];
            for (int nt = 0; nt < 4; nt++) bf[nt] = *(const short8*)&Bs1[(wn + nt * 16 + col) * 32 + quad * 8];
            for (int mt = 0; mt < 4; mt++)
                for (int nt = 0; nt < 4; nt++)
                    acc[mt][nt] = __builtin_amdgcn_mfma_f32_16x16x32_bf16(af[mt], bf[nt], acc[mt][nt], 0, 0, 0);
        }
    }
    for (int mt = 0; mt < 4; mt++)
        for (int nt = 0; nt < 4; nt++)
            for (int r = 0; r < 4; r++) {
                int row = m0 + wm + mt * 16 + quad * 4 + r;
                int cc  = n0 + wn + nt * 16 + col;
                C[(size_t)row * N + cc] = acc[mt][nt][r];
            }
}

// ---------- 4. attention: grid (128 wg, 4 chunks); un-normalized partials ----------
__global__ __launch_bounds__(256) void attn_kernel(
    const short* __restrict__ Q,    // (1024, 512)
    const short* __restrict__ Kb,   // (33792, 512)
    const short* __restrict__ Vt,   // (128*64, 2112)
    float* __restrict__ Opart,      // (512, 64, 64)
    float* __restrict__ Mp,         // (512, 64)
    float* __restrict__ Lp)         // (512, 64)
{
    __shared__ __align__(16) short p_lds[4][64 * 72];   // 36.9 KB; oacc overlays after loop
    __shared__ float sm[4][64];
    __shared__ float sl[4][64];
    float* oacc = (float*)&p_lds[0][0];                 // 16 KB, lifetime-disjoint

    const int wg = blockIdx.x;            // 0..127 = bt*8 + h
    const int ck = blockIdx.y;            // chunk 0..3
    const int wgc = wg * 4 + ck;
    const int bt = wg >> 3, h = wg & 7;
    const int tid = threadIdx.x;
    const int wave = tid >> 6, lane = tid & 63;
    const int col = lane & 15, quad = lane >> 4;

    short8 qf[4][2];
    for (int mt = 0; mt < 4; mt++)
        for (int ks = 0; ks < 2; ks++)
            qf[mt][ks] = *(const short8*)(Q + (size_t)(bt * 64 + mt * 16 + col) * 512
                                            + h * 64 + ks * 32 + quad * 8);

    float m_run[4][4], l_run[4][4];
    f32x4 o_acc[4][4];
    for (int mt = 0; mt < 4; mt++)
        for (int r = 0; r < 4; r++) { m_run[mt][r] = -__builtin_inff(); l_run[mt][r] = 0.f; }
    for (int mt = 0; mt < 4; mt++)
        for (int dt = 0; dt < 4; dt++) o_acc[mt][dt] = f32x4{0.f, 0.f, 0.f, 0.f};

    short* pl = p_lds[wave];

    for (int jb = ck * 4 + wave; jb < 33; jb += 16) {
        f32x4 s[4][4];
        for (int mt = 0; mt < 4; mt++) for (int nt = 0; nt < 4; nt++) s[mt][nt] = f32x4{0.f, 0.f, 0.f, 0.f};
        for (int nt = 0; nt < 4; nt++) {
            const int j = jb * 64 + nt * 16 + col;
            const short* kp = Kb + (size_t)(bt * 2112 + j) * 512 + h * 64 + quad * 8;
            short8 k0 = *(const short8*)kp;
            short8 k1 = *(const short8*)(kp + 32);
            for (int mt = 0; mt < 4; mt++) {
                s[mt][nt] = __builtin_amdgcn_mfma_f32_16x16x32_bf16(qf[mt][0], k0, s[mt][nt], 0, 0, 0);
                s[mt][nt] = __builtin_amdgcn_mfma_f32_16x16x32_bf16(qf[mt][1], k1, s[mt][nt], 0, 0, 0);
            }
        }
        for (int mt = 0; mt < 4; mt++)
            for (int r = 0; r < 4; r++) {
                float mx = fmaxf(fmaxf(s[mt][0][r], s[mt][1][r]), fmaxf(s[mt][2][r], s[mt][3][r]));
                for (int off = 8; off >= 1; off >>= 1) mx = fmaxf(mx, __shfl_xor(mx, off));
                float mnew = fmaxf(m_run[mt][r], mx);
                float alpha = __expf(m_run[mt][r] - mnew);
                float rs = 0.f;
                for (int nt = 0; nt < 4; nt++) {
                    float p = __expf(s[mt][nt][r] - mnew);
                    s[mt][nt][r] = p;
                    rs += p;
                }
                for (int off = 8; off >= 1; off >>= 1) rs += __shfl_xor(rs, off);
                m_run[mt][r] = mnew;
                l_run[mt][r] = l_run[mt][r] * alpha + rs;
                for (int dt = 0; dt < 4; dt++) o_acc[mt][dt][r] *= alpha;
            }
        for (int mt = 0; mt < 4; mt++)
            for (int nt = 0; nt < 4; nt++)
                for (int r = 0; r < 4; r++)
                    pl[(mt * 16 + quad * 4 + r) * 72 + nt * 16 + col] = f2bf(s[mt][nt][r]);
        for (int ks = 0; ks < 2; ks++) {
            short8 vf[4];
            for (int dt = 0; dt < 4; dt++)
                vf[dt] = *(const short8*)(Vt + (size_t)(wg * 64 + dt * 16 + col) * 2112
                                             + jb * 64 + ks * 32 + quad * 8);
            for (int mt = 0; mt < 4; mt++) {
                short8 pf = *(const short8*)(pl + (mt * 16 + col) * 72 + ks * 32 + quad * 8);
                for (int dt = 0; dt < 4; dt++)
                    o_acc[mt][dt] = __builtin_amdgcn_mfma_f32_16x16x32_bf16(pf, vf[dt], o_acc[mt][dt], 0, 0, 0);
            }
        }
    }

    if (col == 0)
        for (int mt = 0; mt < 4; mt++)
            for (int r = 0; r < 4; r++) {
                int row = mt * 16 + quad * 4 + r;
                sm[wave][row] = m_run[mt][r];
                sl[wave][row] = l_run[mt][r];
            }
    __syncthreads();     // p_lds dead after this; oacc (same memory) goes live
    for (int mt = 0; mt < 4; mt++)
        for (int r = 0; r < 4; r++) {
            int row = mt * 16 + quad * 4 + r;
            float M = fmaxf(fmaxf(sm[0][row], sm[1][row]), fmaxf(sm[2][row], sm[3][row]));
            float L = sl[0][row] * __expf(sm[0][row] - M) + sl[1][row] * __expf(sm[1][row] - M)
                    + sl[2][row] * __expf(sm[2][row] - M) + sl[3][row] * __expf(sm[3][row] - M);
            if (wave == 0 && col == 0) { Mp[wgc * 64 + row] = M; Lp[wgc * 64 + row] = L; }
            float sc = __expf(m_run[mt][r] - M);
            for (int dt = 0; dt < 4; dt++) o_acc[mt][dt][r] *= sc;
        }
    for (int i = tid; i < 64 * 64; i += 256) oacc[i] = 0.f;
    __syncthreads();
    for (int w = 0; w < 4; w++) {
        if (wave == w)
            for (int mt = 0; mt < 4; mt++)
                for (int dt = 0; dt < 4; dt++)
                    for (int r = 0; r < 4; r++)
                        oacc[(mt * 16 + quad * 4 + r) * 64 + dt * 16 + col] += o_acc[mt][dt][r];
        __syncthreads();
    }
    for (int i = tid; i < 64 * 64; i += 256)
        Opart[(size_t)wgc * 4096 + i] = oacc[i];
}

// ---------- 5. merge chunk partials -> AttO (bf16) ----------
__global__ __launch_bounds__(256) void attn_merge(
    const float* __restrict__ Opart, const float* __restrict__ Mp,
    const float* __restrict__ Lp, short* __restrict__ AttO)
{
    int idx = blockIdx.x * 256 + threadIdx.x;  // 128*64*64
    int wg = idx >> 12, rd = idx & 4095, row = rd >> 6, d = rd & 63;
    float M = -__builtin_inff();
    for (int c = 0; c < 4; c++) M = fmaxf(M, Mp[(wg * 4 + c) * 64 + row]);
    float L = 0.f, O = 0.f;
    for (int c = 0; c < 4; c++) {
        float e = __expf(Mp[(wg * 4 + c) * 64 + row] - M);
        L += e * Lp[(wg * 4 + c) * 64 + row];
        O += e * Opart[(size_t)(wg * 4 + c) * 4096 + rd];
    }
    int bt = wg >> 3, h = wg & 7;
    AttO[(size_t)(bt * 64 + row) * 512 + h * 64 + d] = f2bf(O / L);
}

// ---------- launch ----------
extern "C" void kernel_launch(void* const* d_in, const int* in_sizes, int n_in,
                              void* d_out, int out_size, void* d_ws, size_t ws_size,
                              hipStream_t stream)
{
    const float* x   = (const float*)d_in[0];
    const float* lat = (const float*)d_in[1];
    const float* g_x = (const float*)d_in[2];
    const float* b_x = (const float*)d_in[3];
    const float* g_l = (const float*)d_in[4];
    const float* b_l = (const float*)d_in[5];
    const float* Wq  = (const float*)d_in[6];
    const float* Wkv = (const float*)d_in[7];
    const float* Wo  = (const float*)d_in[8];
    float* out = (float*)d_out;

    char* ws = (char*)d_ws;
    size_t off = 0;
    auto alloc = [&](size_t bytes) { char* p = ws + off; off += (bytes + 255) & ~(size_t)255; return p; };
    short* A_kvin = (short*)alloc(33792ull * 1024 * 2);  // 69.2 MB
    short* Lq     = (short*)alloc(1024ull * 1024 * 2);
    short* WkvT   = (short*)alloc(1024ull * 1024 * 2);
    short* WqT    = (short*)alloc(512ull * 1024 * 2);
    short* WoT    = (short*)alloc(1024ull * 512 * 2);
    short* Kb     = (short*)alloc(33792ull * 512 * 2);   // 34.6 MB
    short* Vt     = (short*)alloc(33792ull * 512 * 2);   // 34.6 MB (transposed V)
    short* Qb     = (short*)alloc(1024ull * 512 * 2);
    short* AttO   = (short*)alloc(1024ull * 512 * 2);
    float* Opart  = (float*)alloc(512ull * 4096 * 4);    // 8.4 MB
    float* Mp     = (float*)alloc(512ull * 64 * 4);
    float* Lp     = (float*)alloc(512ull * 64 * 4);

    prep_kernel<<<10496, 256, 0, stream>>>(x, lat, g_x, b_x, g_l, b_l, A_kvin, Lq,
                                           Wq, Wkv, Wo, WqT, WkvT, WoT);
    gemm_kvq<<<2144, 256, 0, stream>>>(A_kvin, WkvT, Kb, Vt, Lq, WqT, Qb);
    attn_kernel<<<dim3(128, 4), 256, 0, stream>>>(Qb, Kb, Vt, Opart, Mp, Lp);
    attn_merge<<<2048, 256, 0, stream>>>(Opart, Mp, Lp, AttO);
    gemm_out<<<dim3(8, 8), 256, 0, stream>>>(AttO, WoT, out);
}